// Round 1
// 343.385 us; speedup vs baseline: 1.3264x; 1.3264x over previous
//
#include <hip/hip_runtime.h>

// Problem constants (fixed by reference): B=2, N=8192, C=80
constexpr int NB = 2;
constexpr int NN = 8192;
constexpr int NC = 80;
constexpr int ROWS = NN + 1;  // mask rows per batch; row NN is an all-zero row

// d_out layout (floats), in reference return order:
// boxes[B,N,4], max_scores[B,N], labels[B,N], keep[B,N], all_scores[B,N,C]
constexpr size_t OFF_BOXES  = 0;
constexpr size_t OFF_SCORES = (size_t)NB * NN * 4;
constexpr size_t OFF_LABELS = OFF_SCORES + (size_t)NB * NN;
constexpr size_t OFF_KEEP   = OFF_LABELS + (size_t)NB * NN;
constexpr size_t OFF_ALL    = OFF_KEEP + (size_t)NB * NN;

// d_ws layout
constexpr size_t WS_KEYS  = 0;                                   // B*N u64
constexpr size_t WS_VBYTE = WS_KEYS + (size_t)NB * NN * 8;       // B*N u8
constexpr size_t WS_ORDER = WS_VBYTE + (size_t)NB * NN;          // B*N i32
constexpr size_t WS_SBOX  = WS_ORDER + (size_t)NB * NN * 4;      // B*N float4
constexpr size_t WS_VBITS = WS_SBOX + (size_t)NB * NN * 16;      // B*128 u64
constexpr size_t WS_MASK  = WS_VBITS + (size_t)NB * 128 * 8;     // B*ROWS*128 u64
constexpr size_t WS_DNM   = WS_MASK + (size_t)NB * ROWS * 128 * 8; // B*128*4*64 u64
constexpr size_t WS_TOTAL = WS_DNM + (size_t)NB * 128 * 4 * 64 * 8;
constexpr int DNM_WORDS = NB * 128 * 4 * 64;  // 65536

typedef unsigned long long u64;

// lgkmcnt(0)-only barrier: keeps global loads in flight across it.
// simm16: vmcnt[3:0]=0xF, expcnt=7<<4, lgkmcnt=0<<8, vmcnt[5:4]=3<<14 -> 0xC07F
__device__ inline void lbar() {
  __builtin_amdgcn_s_waitcnt(0xc07f);
  __builtin_amdgcn_s_barrier();
}

__device__ inline u64 readlane64(u64 v, int src) {
  unsigned int lo = (unsigned int)__builtin_amdgcn_readlane((int)(unsigned int)v, src);
  unsigned int hi = (unsigned int)__builtin_amdgcn_readlane((int)(unsigned int)(v >> 32), src);
  return ((u64)hi << 32) | lo;
}

__device__ inline u64 readfirstlane64(u64 v) {
  unsigned int lo = (unsigned int)__builtin_amdgcn_readfirstlane((int)(unsigned int)v);
  unsigned int hi = (unsigned int)__builtin_amdgcn_readfirstlane((int)(unsigned int)(v >> 32));
  return ((u64)hi << 32) | lo;
}

// IoU exactly mirroring the numpy op order; contraction off so f32 rounding
// matches numpy bit-for-bit (keep bits tolerate no error). Note this formula
// is bit-exactly SYMMETRIC in (p,q): fmax/fmin/add are commutative, so the
// lower-triangle column masks equal the transposed upper-triangle rows.
__device__ inline float iou_pair(const float4 p, const float4 q) {
#pragma clang fp contract(off)
  float areaA = (p.z - p.x) * (p.w - p.y);
  float areaB = (q.z - q.x) * (q.w - q.y);
  float ix1 = fmaxf(p.x, q.x);
  float iy1 = fmaxf(p.y, q.y);
  float ix2 = fminf(p.z, q.z);
  float iy2 = fminf(p.w, q.w);
  float inter = fmaxf(ix2 - ix1, 0.0f) * fmaxf(iy2 - iy1, 0.0f);
  float uni = areaA + areaB - inter;
  return inter / fmaxf(uni, 1e-9f);
}

__device__ inline float clip01(float v) { return fminf(fmaxf(v, 0.0f), 1.0f); }

// One wave per (b,n): sigmoid all 80 classes, max/argmax (first-index ties),
// box decode, validity, sort key. Also zero-inits vbits.
__global__ __launch_bounds__(256) void decode_kernel(
    const float* __restrict__ logits, const float4* __restrict__ deltas,
    const float4* __restrict__ anchors, float4* __restrict__ boxes_out,
    float* __restrict__ scores_out, float* __restrict__ labels_out,
    float* __restrict__ all_out, u64* __restrict__ keys,
    unsigned char* __restrict__ vbyte, u64* __restrict__ vbits) {
#pragma clang fp contract(off)
  if (blockIdx.x == 0 && threadIdx.x < NB * 128) vbits[threadIdx.x] = 0ull;
  int wid = (blockIdx.x * 256 + threadIdx.x) >> 6;  // 0 .. B*N-1
  int lane = threadIdx.x & 63;
  int n = wid & (NN - 1);
  size_t base = (size_t)wid * NC;

  float x0 = logits[base + lane];
  float sig0 = 1.0f / (1.0f + expf(-x0));
  all_out[base + lane] = sig0;
  float bs = sig0;
  int bidx = lane;
  if (lane < NC - 64) {
    float x1 = logits[base + 64 + lane];
    float sig1 = 1.0f / (1.0f + expf(-x1));
    all_out[base + 64 + lane] = sig1;
    if (sig1 > bs) { bs = sig1; bidx = lane + 64; }  // tie -> smaller idx wins
  }
  for (int off = 32; off; off >>= 1) {
    float os = __shfl_xor(bs, off, 64);
    int oi = __shfl_xor(bidx, off, 64);
    if (os > bs || (os == bs && oi < bidx)) { bs = os; bidx = oi; }
  }
  if (lane == 0) {
    float4 d = deltas[wid];
    float4 a = anchors[n];
    float aw = a.z - a.x, ah = a.w - a.y;
    float acx = a.x + 0.5f * aw, acy = a.y + 0.5f * ah;
    float dw = fminf(d.z, 4.0f), dh = fminf(d.w, 4.0f);
    float pcx = d.x * aw + acx;
    float pcy = d.y * ah + acy;
    float pw = expf(dw) * aw;
    float ph = expf(dh) * ah;
    float4 bx;
    bx.x = clip01(pcx - 0.5f * pw);
    bx.y = clip01(pcy - 0.5f * ph);
    bx.z = clip01(pcx + 0.5f * pw);
    bx.w = clip01(pcy + 0.5f * ph);
    boxes_out[wid] = bx;
    scores_out[wid] = bs;
    labels_out[wid] = (float)bidx;
    float bw = bx.z - bx.x, bh = bx.w - bx.y;
    bool valid = (bs > 0.5f) && (bw > 0.01f) && (bh > 0.01f) &&
                 (bw < 0.99f) && (bh < 0.99f);
    vbyte[wid] = valid ? 1 : 0;
    // score bits monotone (score>0); tie-break: smaller n first under
    // DESCENDING key sort -> (N-1-n) in low bits. Keys are UNIQUE.
    keys[wid] = ((u64)__float_as_uint(bs) << 32) | (unsigned int)(NN - 1 - n);
  }
}

// Rank sort: rank_i = #{j: key_j > key_i} (keys unique -> permutation).
// Block = 1024 threads = 256 rows x 4 column-quarters; column index is
// wave-uniform -> key loads scalarize. Also zero-inits dnm.
__global__ __launch_bounds__(1024) void rank_kernel(
    const u64* __restrict__ keys, const float4* __restrict__ boxes,
    const unsigned char* __restrict__ vbyte, int* __restrict__ order,
    float4* __restrict__ sbox, u64* __restrict__ vbits,
    u64* __restrict__ dnm) {
  int b = blockIdx.y;
  int gid = (blockIdx.y * gridDim.x + blockIdx.x) * 1024 + threadIdx.x;
  for (int z = gid; z < DNM_WORDS; z += 65536) dnm[z] = 0ull;
  int r = threadIdx.x & 255;   // row slot
  int q = threadIdx.x >> 8;    // column quarter 0..3
  int i = blockIdx.x * 256 + r;
  const u64* kb = keys + (size_t)b * NN;
  u64 myk = kb[i];
  int cnt = 0;
  int j0 = q * (NN / 4), j1 = j0 + NN / 4;
#pragma unroll 8
  for (int j = j0; j < j1; ++j) {
    u64 kj = kb[j];  // wave-uniform address -> scalar load
    cnt += (kj > myk) ? 1 : 0;
  }
  __shared__ unsigned short part[4][256];
  part[q][r] = (unsigned short)cnt;
  __syncthreads();
  if (threadIdx.x < 256) {
    int rank = part[0][r] + part[1][r] + part[2][r] + part[3][r];
    order[(size_t)b * NN + rank] = i;
    sbox[(size_t)b * NN + rank] = boxes[(size_t)b * NN + i];
    if (vbyte[(size_t)b * NN + i])
      atomicOr(&vbits[b * 128 + (rank >> 6)], 1ull << (rank & 63));
  }
}

// 64x64 tile of the (sorted-order) suppression matrix. Triangular grid:
// (128, 65) blocks map bijectively onto the 8256 upper-triangle tiles
// (lower-triangle launches were pure dispatch waste). Diagonal tiles now
// compute the FULL symmetric row: upper half goes to mask[] (dead data for
// the bg waves, kept tidy), LOWER half goes to dnm slot 0 — it is the
// column mask ("who above me suppresses me") consumed by reduce's ballot
// fixpoint. Off-diag tiles with bx-by in {1..3} also write compact dnm.
__global__ __launch_bounds__(64) void build_kernel(
    const float4* __restrict__ sbox, u64* __restrict__ mask,
    u64* __restrict__ dnm) {
  int byq = blockIdx.y, bxq = blockIdx.x, b = blockIdx.z;
  int by, bx;
  if (bxq >= byq) {
    by = byq; bx = bxq;
  } else if (byq == 64) {
    return;  // 64 spare blocks in the triangular mapping
  } else {
    by = 128 - byq; bx = 127 - bxq;  // mirrored lower-left -> upper rows 65..127
  }
  int lane = threadIdx.x;
  __shared__ float4 cb[64];
  cb[lane] = sbox[(size_t)b * NN + bx * 64 + lane];
  __syncthreads();
  int i = by * 64 + lane;
  float4 rb = sbox[(size_t)b * NN + i];
  u64 word = 0;
  if (bx == by) {
    for (int jj = 0; jj < 64; ++jj)
      if (iou_pair(rb, cb[jj]) > 0.5f) word |= 1ull << jj;
    word &= ~(1ull << lane);  // clear self-IoU bit
    u64 lmask = (1ull << lane) - 1ull;
    mask[((size_t)b * ROWS + i) * 128 + bx] = word & ~lmask;
    dnm[(((size_t)b * 128 + by) * 4 + 0) * 64 + lane] = word & lmask;
  } else {
    for (int jj = 0; jj < 64; ++jj)
      if (iou_pair(rb, cb[jj]) > 0.5f) word |= 1ull << jj;
    mask[((size_t)b * ROWS + i) * 128 + bx] = word;
    int dq = bx - by;
    if (dq < 4) dnm[(((size_t)b * 128 + by) * 4 + dq) * 64 + lane] = word;
  }
}

struct TSet {
  ulonglong2 t0, t1, t2, t3, t4, t5, t6, t7, t8, t9;
};

// Greedy reduce v8: one 512-thread block per batch, one lgkm-only barrier
// per chunk; background pipeline has TWO chunks of load slack.
//  - Wave 0: in-chunk greedy via BALLOT FIXPOINT (replaces the ~60-iteration
//    serial readlane bit-loop of v7). Greedy NMS within a chunk is the
//    unique fixpoint of F(K)[l] = cand[l] & !(low_l & K) where low_l is
//    lane l's lower-triangle column mask (from dnm slot 0). Iterating
//    K <- cand & ~ballot(low_l & K) from K0=cand converges exactly to the
//    greedy set: the first index where K disagrees with greedy strictly
//    increases each iteration (<=64 iters; ~3-5 on sparse random overlaps).
//    Kept lanes deposit words c+1..c+3 via LDS atomicOr as before.
//  - Waves 1..7: at chunk c ISSUE rows of chunk c-1 (rowlist published at
//    c-1) into register set U/V (alternating by body parity); CONSUME the
//    set issued at c-2 (rows of chunk c-3) into words > c.
__global__ __launch_bounds__(512) void reduce_kernel(
    u64* __restrict__ mask, const u64* __restrict__ vbits,
    const u64* __restrict__ dnm, const int* __restrict__ order,
    float* __restrict__ keep_out) {
  int b = blockIdx.x, tid = threadIdx.x;
  int lane = tid & 63, wave = tid >> 6;
  __shared__ u64 s_remv[128];
  __shared__ u64 s_keep[128];
  __shared__ int s_rowlist[2][80];
  __shared__ int s_nk[2];
  u64* mbz = mask + (size_t)b * ROWS * 128;
  const u64* mb = mbz;
  const u64* dn = dnm + (size_t)b * 128 * 4 * 64;

  for (int w = tid; w < 128; w += 512) {
    s_remv[w] = 0ull;
    mbz[(size_t)NN * 128 + w] = 0ull;  // zero row (padded rowlist target)
  }
  if (tid < 2) s_nk[tid] = 0;
  if (tid < 160) s_rowlist[tid / 80][tid % 80] = NN;

  // Wave 0 state: vbits in regs; 4 rotating prefetch slots of (d,n,m,o).
  u64 va = 0, vb2 = 0;
  u64 dA = 0, nA = 0, mA = 0, oA = 0, dB = 0, nB = 0, mB = 0, oB = 0;
  u64 dC = 0, nC = 0, mC = 0, oC = 0, dD = 0, nD = 0, mD = 0, oD = 0;
  if (wave == 0) {
    va = vbits[b * 128 + 2 * lane];
    vb2 = vbits[b * 128 + 2 * lane + 1];
    const u64* r0 = dn + lane;  // chunk 0
    dA = r0[0]; nA = r0[64]; mA = r0[128]; oA = r0[192];
    const u64* r1 = dn + 4 * 64 + lane;  // chunk 1
    dB = r1[0]; nB = r1[64]; mB = r1[128]; oB = r1[192];
  }
  TSet U{}, V{};  // background in-flight sets (even / odd bodies)
  int w0i = 2 * lane, w1i = 2 * lane + 1;
  __syncthreads();  // full barrier: zero-row global write + LDS init visible

  // Serial body for chunk c: use (dcur..ocur); prefetch chunk c+2 into the
  // (c+2)%4 slot (its previous value died at body c-2) -> no copies/selects.
  auto serial_body = [&](int c, u64 dcur, u64 ncur, u64 mcur, u64 ocur,
                         u64& dnew, u64& nnew, u64& mnew, u64& onew) {
    if (c + 2 < 128) {  // issue first, consume 2 chunks later
      const u64* rp = dn + (size_t)(c + 2) * 4 * 64 + lane;
      dnew = rp[0]; nnew = rp[64]; mnew = rp[128]; onew = rp[192];
    } else {
      dnew = 0; nnew = 0; mnew = 0; onew = 0;
    }
    int par = c & 1;
    u64 rm = s_remv[c];  // LDS broadcast read
    u64 vbw = readlane64(par ? vb2 : va, c >> 1);
    u64 cand = readfirstlane64(vbw & ~rm);  // uniform -> SGPR domain
    // Ballot fixpoint: dcur = lane's lower-triangle column mask.
    u64 kept = cand;
    while (true) {
      u64 sup = __ballot((dcur & kept) != 0ull);
      u64 nk = cand & ~sup;
      if (nk == kept) break;
      kept = nk;
    }
    bool isk = (kept >> lane) & 1;
    if (c + 1 < 128 && isk && ncur) atomicOr(&s_remv[c + 1], ncur);
    if (c + 2 < 128 && isk && mcur) atomicOr(&s_remv[c + 2], mcur);
    if (c + 3 < 128 && isk && ocur) atomicOr(&s_remv[c + 3], ocur);
    s_rowlist[par][lane] = NN;  // pad; kept positions overwrite below
    if (isk) {
      int pos = __popcll(kept & ((1ull << lane) - 1ull));
      s_rowlist[par][pos] = c * 64 + lane;
    }
    if (lane == 0) {
      s_keep[c] = kept;
      s_nk[par] = __popcll(kept);
    }
  };

  auto bg_body = [&](int c, TSet& T) {
    // consume T (rows of chunk c-3, issued at body c-2) into words > c
    u64 ax = T.t0.x | T.t1.x | T.t2.x | T.t3.x | T.t4.x | T.t5.x | T.t6.x |
             T.t7.x | T.t8.x | T.t9.x;
    u64 ay = T.t0.y | T.t1.y | T.t2.y | T.t3.y | T.t4.y | T.t5.y | T.t6.y |
             T.t7.y | T.t8.y | T.t9.y;
    if (w0i > c && ax) atomicOr(&s_remv[w0i], ax);
    if (w1i > c && ay) atomicOr(&s_remv[w1i], ay);
    // issue loads for rows of chunk c-1 (consumed at body c+2, words > c+2)
    int nk1 = s_nk[(c - 1) & 1];  // c=0 -> slot 1 = 0
    T = TSet{};
    if (nk1 > 0 && w1i > c + 2) {
      const int* rl = s_rowlist[(c - 1) & 1];
      int base = wave - 1;  // waves 1..7 -> 0..6; stride 7 covers 0..69
      int r0 = rl[base], r1 = rl[base + 7], r2 = rl[base + 14],
          r3 = rl[base + 21], r4 = rl[base + 28], r5 = rl[base + 35],
          r6 = rl[base + 42], r7 = rl[base + 49], r8 = rl[base + 56],
          r9 = rl[base + 63];
      T.t0 = *(const ulonglong2*)(mb + (size_t)r0 * 128 + w0i);
      T.t1 = *(const ulonglong2*)(mb + (size_t)r1 * 128 + w0i);
      T.t2 = *(const ulonglong2*)(mb + (size_t)r2 * 128 + w0i);
      T.t3 = *(const ulonglong2*)(mb + (size_t)r3 * 128 + w0i);
      T.t4 = *(const ulonglong2*)(mb + (size_t)r4 * 128 + w0i);
      T.t5 = *(const ulonglong2*)(mb + (size_t)r5 * 128 + w0i);
      T.t6 = *(const ulonglong2*)(mb + (size_t)r6 * 128 + w0i);
      T.t7 = *(const ulonglong2*)(mb + (size_t)r7 * 128 + w0i);
      T.t8 = *(const ulonglong2*)(mb + (size_t)r8 * 128 + w0i);
      T.t9 = *(const ulonglong2*)(mb + (size_t)r9 * 128 + w0i);
    }
  };

  for (int c = 0; c < 128; c += 4) {
    if (wave == 0) serial_body(c, dA, nA, mA, oA, dC, nC, mC, oC);
    else bg_body(c, U);
    lbar();
    if (wave == 0) serial_body(c + 1, dB, nB, mB, oB, dD, nD, mD, oD);
    else bg_body(c + 1, V);
    lbar();
    if (wave == 0) serial_body(c + 2, dC, nC, mC, oC, dA, nA, mA, oA);
    else bg_body(c + 2, U);
    lbar();
    if (wave == 0) serial_body(c + 3, dD, nD, mD, oD, dB, nB, mB, oB);
    else bg_body(c + 3, V);
    lbar();
  }

  // scatter keep flags back to original anchor order
  for (int p = tid; p < NN; p += 512) {
    int orig = order[(size_t)b * NN + p];
    keep_out[(size_t)b * NN + orig] =
        ((s_keep[p >> 6] >> (p & 63)) & 1) ? 1.0f : 0.0f;
  }
}

// Slow-but-correct fallback if d_ws can't hold the mask: classic iterative
// greedy NMS, one block per batch.
__global__ __launch_bounds__(1024) void nms_fallback(
    const float4* __restrict__ sbox, const u64* __restrict__ vbits,
    const int* __restrict__ order, float* __restrict__ keep_out) {
  int b = blockIdx.x, tid = threadIdx.x;
  __shared__ u64 dead[128];
  __shared__ int s_next;
  __shared__ float4 s_box;
  for (int w = tid; w < 128; w += 1024) dead[w] = ~vbits[b * 128 + w];
  for (int p = tid; p < NN; p += 1024)
    keep_out[(size_t)b * NN + order[(size_t)b * NN + p]] = 0.0f;
  __syncthreads();
  int i = 0;
  while (true) {
    if (tid == 0) {
      int nxt = NN;
      int w = i >> 6;
      u64 live = ~dead[w] & (~0ull << (i & 63));
      while (true) {
        if (live) { nxt = w * 64 + __builtin_ctzll(live); break; }
        if (++w >= 128) break;
        live = ~dead[w];
      }
      s_next = nxt;
      if (nxt < NN) {
        s_box = sbox[(size_t)b * NN + nxt];
        keep_out[(size_t)b * NN + order[(size_t)b * NN + nxt]] = 1.0f;
      }
    }
    __syncthreads();
    i = s_next;
    if (i >= NN) break;
    float4 kb = s_box;
    for (int j = i + 1 + tid; j < NN; j += 1024) {
      if (iou_pair(kb, sbox[(size_t)b * NN + j]) > 0.5f)
        atomicOr(&dead[j >> 6], 1ull << (j & 63));
    }
    __syncthreads();
    i = i + 1;
  }
}

extern "C" void kernel_launch(void* const* d_in, const int* in_sizes, int n_in,
                              void* d_out, int out_size, void* d_ws, size_t ws_size,
                              hipStream_t stream) {
  const float* logits = (const float*)d_in[0];
  const float4* deltas = (const float4*)d_in[1];
  const float4* anchors = (const float4*)d_in[2];
  float* out = (float*)d_out;
  float4* boxes_out = (float4*)(out + OFF_BOXES);
  float* scores_out = out + OFF_SCORES;
  float* labels_out = out + OFF_LABELS;
  float* keep_out = out + OFF_KEEP;
  float* all_out = out + OFF_ALL;

  char* ws = (char*)d_ws;
  u64* keys = (u64*)(ws + WS_KEYS);
  unsigned char* vbyte = (unsigned char*)(ws + WS_VBYTE);
  int* order = (int*)(ws + WS_ORDER);
  float4* sbox = (float4*)(ws + WS_SBOX);
  u64* vbits = (u64*)(ws + WS_VBITS);
  u64* mask = (u64*)(ws + WS_MASK);
  u64* dnm = (u64*)(ws + WS_DNM);

  decode_kernel<<<dim3(NB * NN / 4), dim3(256), 0, stream>>>(
      logits, deltas, anchors, boxes_out, scores_out, labels_out, all_out,
      keys, vbyte, vbits);
  rank_kernel<<<dim3(NN / 256, NB), dim3(1024), 0, stream>>>(
      keys, (const float4*)boxes_out, vbyte, order, sbox, vbits, dnm);
  if (ws_size >= WS_TOTAL) {
    build_kernel<<<dim3(128, 65, NB), dim3(64), 0, stream>>>(sbox, mask, dnm);
    reduce_kernel<<<dim3(NB), dim3(512), 0, stream>>>(mask, vbits, dnm, order,
                                                      keep_out);
  } else {
    nms_fallback<<<dim3(NB), dim3(1024), 0, stream>>>(sbox, vbits, order,
                                                      keep_out);
  }
}

// Round 2
// 263.604 us; speedup vs baseline: 1.7279x; 1.3027x over previous
//
#include <hip/hip_runtime.h>

// Problem constants (fixed by reference): B=2, N=8192, C=80
constexpr int NB = 2;
constexpr int NN = 8192;
constexpr int NC = 80;
constexpr int ROWS = NN + 1;  // mask rows per batch; row NN is an all-zero row

// d_out layout (floats), in reference return order:
// boxes[B,N,4], max_scores[B,N], labels[B,N], keep[B,N], all_scores[B,N,C]
constexpr size_t OFF_BOXES  = 0;
constexpr size_t OFF_SCORES = (size_t)NB * NN * 4;
constexpr size_t OFF_LABELS = OFF_SCORES + (size_t)NB * NN;
constexpr size_t OFF_KEEP   = OFF_LABELS + (size_t)NB * NN;
constexpr size_t OFF_ALL    = OFF_KEEP + (size_t)NB * NN;

// d_ws layout
constexpr size_t WS_KEYS  = 0;                                   // B*N u64
constexpr size_t WS_VBYTE = WS_KEYS + (size_t)NB * NN * 8;       // B*N u8
constexpr size_t WS_ORDER = WS_VBYTE + (size_t)NB * NN;          // B*N i32
constexpr size_t WS_SBOX  = WS_ORDER + (size_t)NB * NN * 4;      // B*N float4
constexpr size_t WS_VBITS = WS_SBOX + (size_t)NB * NN * 16;      // B*128 u64
constexpr size_t WS_MASK  = WS_VBITS + (size_t)NB * 128 * 8;     // B*ROWS*128 u64
constexpr size_t WS_DNM   = WS_MASK + (size_t)NB * ROWS * 128 * 8; // B*128*4*64 u64
constexpr size_t WS_PART  = WS_DNM + (size_t)NB * 128 * 4 * 64 * 8; // B*8*N i32
constexpr size_t WS_TOTAL = WS_PART + (size_t)NB * 8 * NN * 4;
// Old (single-kernel-rank) total, for the fallback gate:
constexpr size_t WS_TOTAL_OLD = WS_PART;
constexpr int DNM_WORDS = NB * 128 * 4 * 64;  // 65536
constexpr int NSEG = 8;                       // rank column segments

typedef unsigned long long u64;

// lgkmcnt(0)-only barrier: keeps global loads in flight across it.
// simm16: vmcnt[3:0]=0xF, expcnt=7<<4, lgkmcnt=0<<8, vmcnt[5:4]=3<<14 -> 0xC07F
__device__ inline void lbar() {
  __builtin_amdgcn_s_waitcnt(0xc07f);
  __builtin_amdgcn_s_barrier();
}

__device__ inline u64 readlane64(u64 v, int src) {
  unsigned int lo = (unsigned int)__builtin_amdgcn_readlane((int)(unsigned int)v, src);
  unsigned int hi = (unsigned int)__builtin_amdgcn_readlane((int)(unsigned int)(v >> 32), src);
  return ((u64)hi << 32) | lo;
}

__device__ inline u64 readfirstlane64(u64 v) {
  unsigned int lo = (unsigned int)__builtin_amdgcn_readfirstlane((int)(unsigned int)v);
  unsigned int hi = (unsigned int)__builtin_amdgcn_readfirstlane((int)(unsigned int)(v >> 32));
  return ((u64)hi << 32) | lo;
}

// IoU exactly mirroring the numpy op order; contraction off so f32 rounding
// matches numpy bit-for-bit (keep bits tolerate no error). Note this formula
// is bit-exactly SYMMETRIC in (p,q): fmax/fmin/add are commutative, so the
// lower-triangle column masks equal the transposed upper-triangle rows.
__device__ inline float iou_pair(const float4 p, const float4 q) {
#pragma clang fp contract(off)
  float areaA = (p.z - p.x) * (p.w - p.y);
  float areaB = (q.z - q.x) * (q.w - q.y);
  float ix1 = fmaxf(p.x, q.x);
  float iy1 = fmaxf(p.y, q.y);
  float ix2 = fminf(p.z, q.z);
  float iy2 = fminf(p.w, q.w);
  float inter = fmaxf(ix2 - ix1, 0.0f) * fmaxf(iy2 - iy1, 0.0f);
  float uni = areaA + areaB - inter;
  return inter / fmaxf(uni, 1e-9f);
}

__device__ inline float clip01(float v) { return fminf(fmaxf(v, 0.0f), 1.0f); }

// One wave per (b,n): sigmoid all 80 classes, max/argmax (first-index ties),
// box decode, validity, sort key. Also zero-inits vbits.
__global__ __launch_bounds__(256) void decode_kernel(
    const float* __restrict__ logits, const float4* __restrict__ deltas,
    const float4* __restrict__ anchors, float4* __restrict__ boxes_out,
    float* __restrict__ scores_out, float* __restrict__ labels_out,
    float* __restrict__ all_out, u64* __restrict__ keys,
    unsigned char* __restrict__ vbyte, u64* __restrict__ vbits) {
#pragma clang fp contract(off)
  if (blockIdx.x == 0 && threadIdx.x < NB * 128) vbits[threadIdx.x] = 0ull;
  int wid = (blockIdx.x * 256 + threadIdx.x) >> 6;  // 0 .. B*N-1
  int lane = threadIdx.x & 63;
  int n = wid & (NN - 1);
  size_t base = (size_t)wid * NC;

  float x0 = logits[base + lane];
  float sig0 = 1.0f / (1.0f + expf(-x0));
  all_out[base + lane] = sig0;
  float bs = sig0;
  int bidx = lane;
  if (lane < NC - 64) {
    float x1 = logits[base + 64 + lane];
    float sig1 = 1.0f / (1.0f + expf(-x1));
    all_out[base + 64 + lane] = sig1;
    if (sig1 > bs) { bs = sig1; bidx = lane + 64; }  // tie -> smaller idx wins
  }
  for (int off = 32; off; off >>= 1) {
    float os = __shfl_xor(bs, off, 64);
    int oi = __shfl_xor(bidx, off, 64);
    if (os > bs || (os == bs && oi < bidx)) { bs = os; bidx = oi; }
  }
  if (lane == 0) {
    float4 d = deltas[wid];
    float4 a = anchors[n];
    float aw = a.z - a.x, ah = a.w - a.y;
    float acx = a.x + 0.5f * aw, acy = a.y + 0.5f * ah;
    float dw = fminf(d.z, 4.0f), dh = fminf(d.w, 4.0f);
    float pcx = d.x * aw + acx;
    float pcy = d.y * ah + acy;
    float pw = expf(dw) * aw;
    float ph = expf(dh) * ah;
    float4 bx;
    bx.x = clip01(pcx - 0.5f * pw);
    bx.y = clip01(pcy - 0.5f * ph);
    bx.z = clip01(pcx + 0.5f * pw);
    bx.w = clip01(pcy + 0.5f * ph);
    boxes_out[wid] = bx;
    scores_out[wid] = bs;
    labels_out[wid] = (float)bidx;
    float bw = bx.z - bx.x, bh = bx.w - bx.y;
    bool valid = (bs > 0.5f) && (bw > 0.01f) && (bh > 0.01f) &&
                 (bw < 0.99f) && (bh < 0.99f);
    vbyte[wid] = valid ? 1 : 0;
    // score bits monotone (score>0); tie-break: smaller n first under
    // DESCENDING key sort -> (N-1-n) in low bits. Keys are UNIQUE.
    keys[wid] = ((u64)__float_as_uint(bs) << 32) | (unsigned int)(NN - 1 - n);
  }
}

// Rank pass 1: partial counts over a column SEGMENT. Grid (32 rowblocks,
// NSEG colsegs, NB); block = 1024 threads = 256 rows x 4 quarters. The
// per-thread scalar-load chain is 8x shorter than the monolithic version
// and 8x more blocks occupy the chip. Column index is wave-uniform ->
// key loads scalarize. Also zero-inits dnm.
__global__ __launch_bounds__(1024) void rank_part_kernel(
    const u64* __restrict__ keys, int* __restrict__ part,
    u64* __restrict__ dnm) {
  int b = blockIdx.z, seg = blockIdx.y, rb = blockIdx.x;
  int gid = ((blockIdx.z * NSEG + blockIdx.y) * gridDim.x + blockIdx.x) * 1024 +
            threadIdx.x;
  if (gid < DNM_WORDS) dnm[gid] = 0ull;
  int r = threadIdx.x & 255;   // row slot
  int q = threadIdx.x >> 8;    // column quarter 0..3 (wave-uniform)
  int i = rb * 256 + r;
  const u64* kb = keys + (size_t)b * NN;
  u64 myk = kb[i];
  int cnt = 0;
  int j0 = seg * (NN / NSEG) + q * (NN / NSEG / 4);
  int j1 = j0 + NN / NSEG / 4;  // 256 iterations
#pragma unroll 8
  for (int j = j0; j < j1; ++j) {
    u64 kj = kb[j];  // wave-uniform address -> scalar load
    cnt += (kj > myk) ? 1 : 0;
  }
  __shared__ unsigned short partl[4][256];
  partl[q][r] = (unsigned short)cnt;
  __syncthreads();
  if (threadIdx.x < 256) {
    int s = partl[0][r] + partl[1][r] + partl[2][r] + partl[3][r];
    part[((size_t)b * NSEG + seg) * NN + i] = s;
  }
}

// Rank pass 2: rank_i = sum of segment partials (keys unique -> permutation);
// scatter order/sbox/vbits.
__global__ __launch_bounds__(256) void rank_final_kernel(
    const int* __restrict__ part, const float4* __restrict__ boxes,
    const unsigned char* __restrict__ vbyte, int* __restrict__ order,
    float4* __restrict__ sbox, u64* __restrict__ vbits) {
  int b = blockIdx.y;
  int i = blockIdx.x * 256 + threadIdx.x;
  const int* pb = part + (size_t)b * NSEG * NN + i;
  int rank = 0;
#pragma unroll
  for (int s = 0; s < NSEG; ++s) rank += pb[(size_t)s * NN];
  order[(size_t)b * NN + rank] = i;
  sbox[(size_t)b * NN + rank] = boxes[(size_t)b * NN + i];
  if (vbyte[(size_t)b * NN + i])
    atomicOr(&vbits[b * 128 + (rank >> 6)], 1ull << (rank & 63));
}

// Monolithic rank (fallback path only, when ws can't hold part[]).
__global__ __launch_bounds__(1024) void rank_kernel(
    const u64* __restrict__ keys, const float4* __restrict__ boxes,
    const unsigned char* __restrict__ vbyte, int* __restrict__ order,
    float4* __restrict__ sbox, u64* __restrict__ vbits,
    u64* __restrict__ dnm) {
  int b = blockIdx.y;
  int gid = (blockIdx.y * gridDim.x + blockIdx.x) * 1024 + threadIdx.x;
  for (int z = gid; z < DNM_WORDS; z += 65536) dnm[z] = 0ull;
  int r = threadIdx.x & 255;   // row slot
  int q = threadIdx.x >> 8;    // column quarter 0..3
  int i = blockIdx.x * 256 + r;
  const u64* kb = keys + (size_t)b * NN;
  u64 myk = kb[i];
  int cnt = 0;
  int j0 = q * (NN / 4), j1 = j0 + NN / 4;
#pragma unroll 8
  for (int j = j0; j < j1; ++j) {
    u64 kj = kb[j];  // wave-uniform address -> scalar load
    cnt += (kj > myk) ? 1 : 0;
  }
  __shared__ unsigned short part[4][256];
  part[q][r] = (unsigned short)cnt;
  __syncthreads();
  if (threadIdx.x < 256) {
    int rank = part[0][r] + part[1][r] + part[2][r] + part[3][r];
    order[(size_t)b * NN + rank] = i;
    sbox[(size_t)b * NN + rank] = boxes[(size_t)b * NN + i];
    if (vbyte[(size_t)b * NN + i])
      atomicOr(&vbits[b * 128 + (rank >> 6)], 1ull << (rank & 63));
  }
}

// 64x64 tile of the (sorted-order) suppression matrix. Triangular grid:
// (128, 65) blocks map bijectively onto the 8256 upper-triangle tiles.
// Diagonal tiles compute the FULL symmetric row: upper half to mask[],
// LOWER half to dnm slot 0 — the column mask ("who above me suppresses me")
// consumed by reduce's ballot fixpoint. Off-diag tiles with bx-by in {1..3}
// also write compact dnm.
__global__ __launch_bounds__(64) void build_kernel(
    const float4* __restrict__ sbox, u64* __restrict__ mask,
    u64* __restrict__ dnm) {
  int byq = blockIdx.y, bxq = blockIdx.x, b = blockIdx.z;
  int by, bx;
  if (bxq >= byq) {
    by = byq; bx = bxq;
  } else if (byq == 64) {
    return;  // 64 spare blocks in the triangular mapping
  } else {
    by = 128 - byq; bx = 127 - bxq;  // mirrored lower-left -> upper rows 65..127
  }
  int lane = threadIdx.x;
  __shared__ float4 cb[64];
  cb[lane] = sbox[(size_t)b * NN + bx * 64 + lane];
  __syncthreads();
  int i = by * 64 + lane;
  float4 rb = sbox[(size_t)b * NN + i];
  u64 word = 0;
  if (bx == by) {
    for (int jj = 0; jj < 64; ++jj)
      if (iou_pair(rb, cb[jj]) > 0.5f) word |= 1ull << jj;
    word &= ~(1ull << lane);  // clear self-IoU bit
    u64 lmask = (1ull << lane) - 1ull;
    mask[((size_t)b * ROWS + i) * 128 + bx] = word & ~lmask;
    dnm[(((size_t)b * 128 + by) * 4 + 0) * 64 + lane] = word & lmask;
  } else {
    for (int jj = 0; jj < 64; ++jj)
      if (iou_pair(rb, cb[jj]) > 0.5f) word |= 1ull << jj;
    mask[((size_t)b * ROWS + i) * 128 + bx] = word;
    int dq = bx - by;
    if (dq < 4) dnm[(((size_t)b * 128 + by) * 4 + dq) * 64 + lane] = word;
  }
}

struct TSet {
  ulonglong2 t0, t1, t2, t3, t4, t5, t6, t7, t8, t9;
};

// Greedy reduce v8: one 512-thread block per batch, one lgkm-only barrier
// per chunk; background pipeline has TWO chunks of load slack.
//  - Wave 0: in-chunk greedy via BALLOT FIXPOINT. Greedy NMS within a chunk
//    is the unique fixpoint of F(K)[l] = cand[l] & !(low_l & K) where low_l
//    is lane l's lower-triangle column mask (from dnm slot 0). Iterating
//    K <- cand & ~ballot(low_l & K) from K0=cand converges exactly to the
//    greedy set (<=64 iters; ~3-5 on sparse random overlaps). Kept lanes
//    deposit words c+1..c+3 via LDS atomicOr.
//  - Waves 1..7: at chunk c ISSUE rows of chunk c-1 (rowlist published at
//    c-1) into register set U/V (alternating by body parity); CONSUME the
//    set issued at c-2 (rows of chunk c-3) into words > c.
__global__ __launch_bounds__(512) void reduce_kernel(
    u64* __restrict__ mask, const u64* __restrict__ vbits,
    const u64* __restrict__ dnm, const int* __restrict__ order,
    float* __restrict__ keep_out) {
  int b = blockIdx.x, tid = threadIdx.x;
  int lane = tid & 63, wave = tid >> 6;
  __shared__ u64 s_remv[128];
  __shared__ u64 s_keep[128];
  __shared__ int s_rowlist[2][80];
  __shared__ int s_nk[2];
  u64* mbz = mask + (size_t)b * ROWS * 128;
  const u64* mb = mbz;
  const u64* dn = dnm + (size_t)b * 128 * 4 * 64;

  for (int w = tid; w < 128; w += 512) {
    s_remv[w] = 0ull;
    mbz[(size_t)NN * 128 + w] = 0ull;  // zero row (padded rowlist target)
  }
  if (tid < 2) s_nk[tid] = 0;
  if (tid < 160) s_rowlist[tid / 80][tid % 80] = NN;

  // Wave 0 state: vbits in regs; 4 rotating prefetch slots of (d,n,m,o).
  u64 va = 0, vb2 = 0;
  u64 dA = 0, nA = 0, mA = 0, oA = 0, dB = 0, nB = 0, mB = 0, oB = 0;
  u64 dC = 0, nC = 0, mC = 0, oC = 0, dD = 0, nD = 0, mD = 0, oD = 0;
  if (wave == 0) {
    va = vbits[b * 128 + 2 * lane];
    vb2 = vbits[b * 128 + 2 * lane + 1];
    const u64* r0 = dn + lane;  // chunk 0
    dA = r0[0]; nA = r0[64]; mA = r0[128]; oA = r0[192];
    const u64* r1 = dn + 4 * 64 + lane;  // chunk 1
    dB = r1[0]; nB = r1[64]; mB = r1[128]; oB = r1[192];
  }
  TSet U{}, V{};  // background in-flight sets (even / odd bodies)
  int w0i = 2 * lane, w1i = 2 * lane + 1;
  __syncthreads();  // full barrier: zero-row global write + LDS init visible

  // Serial body for chunk c: use (dcur..ocur); prefetch chunk c+2 into the
  // (c+2)%4 slot (its previous value died at body c-2) -> no copies/selects.
  auto serial_body = [&](int c, u64 dcur, u64 ncur, u64 mcur, u64 ocur,
                         u64& dnew, u64& nnew, u64& mnew, u64& onew) {
    if (c + 2 < 128) {  // issue first, consume 2 chunks later
      const u64* rp = dn + (size_t)(c + 2) * 4 * 64 + lane;
      dnew = rp[0]; nnew = rp[64]; mnew = rp[128]; onew = rp[192];
    } else {
      dnew = 0; nnew = 0; mnew = 0; onew = 0;
    }
    int par = c & 1;
    u64 rm = s_remv[c];  // LDS broadcast read
    u64 vbw = readlane64(par ? vb2 : va, c >> 1);
    u64 cand = readfirstlane64(vbw & ~rm);  // uniform -> SGPR domain
    // Ballot fixpoint: dcur = lane's lower-triangle column mask.
    u64 kept = cand;
    while (true) {
      u64 sup = __ballot((dcur & kept) != 0ull);
      u64 nk = cand & ~sup;
      if (nk == kept) break;
      kept = nk;
    }
    bool isk = (kept >> lane) & 1;
    if (c + 1 < 128 && isk && ncur) atomicOr(&s_remv[c + 1], ncur);
    if (c + 2 < 128 && isk && mcur) atomicOr(&s_remv[c + 2], mcur);
    if (c + 3 < 128 && isk && ocur) atomicOr(&s_remv[c + 3], ocur);
    s_rowlist[par][lane] = NN;  // pad; kept positions overwrite below
    if (isk) {
      int pos = __popcll(kept & ((1ull << lane) - 1ull));
      s_rowlist[par][pos] = c * 64 + lane;
    }
    if (lane == 0) {
      s_keep[c] = kept;
      s_nk[par] = __popcll(kept);
    }
  };

  auto bg_body = [&](int c, TSet& T) {
    // consume T (rows of chunk c-3, issued at body c-2) into words > c
    u64 ax = T.t0.x | T.t1.x | T.t2.x | T.t3.x | T.t4.x | T.t5.x | T.t6.x |
             T.t7.x | T.t8.x | T.t9.x;
    u64 ay = T.t0.y | T.t1.y | T.t2.y | T.t3.y | T.t4.y | T.t5.y | T.t6.y |
             T.t7.y | T.t8.y | T.t9.y;
    if (w0i > c && ax) atomicOr(&s_remv[w0i], ax);
    if (w1i > c && ay) atomicOr(&s_remv[w1i], ay);
    // issue loads for rows of chunk c-1 (consumed at body c+2, words > c+2)
    int nk1 = s_nk[(c - 1) & 1];  // c=0 -> slot 1 = 0
    T = TSet{};
    if (nk1 > 0 && w1i > c + 2) {
      const int* rl = s_rowlist[(c - 1) & 1];
      int base = wave - 1;  // waves 1..7 -> 0..6; stride 7 covers 0..69
      int r0 = rl[base], r1 = rl[base + 7], r2 = rl[base + 14],
          r3 = rl[base + 21], r4 = rl[base + 28], r5 = rl[base + 35],
          r6 = rl[base + 42], r7 = rl[base + 49], r8 = rl[base + 56],
          r9 = rl[base + 63];
      T.t0 = *(const ulonglong2*)(mb + (size_t)r0 * 128 + w0i);
      T.t1 = *(const ulonglong2*)(mb + (size_t)r1 * 128 + w0i);
      T.t2 = *(const ulonglong2*)(mb + (size_t)r2 * 128 + w0i);
      T.t3 = *(const ulonglong2*)(mb + (size_t)r3 * 128 + w0i);
      T.t4 = *(const ulonglong2*)(mb + (size_t)r4 * 128 + w0i);
      T.t5 = *(const ulonglong2*)(mb + (size_t)r5 * 128 + w0i);
      T.t6 = *(const ulonglong2*)(mb + (size_t)r6 * 128 + w0i);
      T.t7 = *(const ulonglong2*)(mb + (size_t)r7 * 128 + w0i);
      T.t8 = *(const ulonglong2*)(mb + (size_t)r8 * 128 + w0i);
      T.t9 = *(const ulonglong2*)(mb + (size_t)r9 * 128 + w0i);
    }
  };

  for (int c = 0; c < 128; c += 4) {
    if (wave == 0) serial_body(c, dA, nA, mA, oA, dC, nC, mC, oC);
    else bg_body(c, U);
    lbar();
    if (wave == 0) serial_body(c + 1, dB, nB, mB, oB, dD, nD, mD, oD);
    else bg_body(c + 1, V);
    lbar();
    if (wave == 0) serial_body(c + 2, dC, nC, mC, oC, dA, nA, mA, oA);
    else bg_body(c + 2, U);
    lbar();
    if (wave == 0) serial_body(c + 3, dD, nD, mD, oD, dB, nB, mB, oB);
    else bg_body(c + 3, V);
    lbar();
  }

  // scatter keep flags back to original anchor order
  for (int p = tid; p < NN; p += 512) {
    int orig = order[(size_t)b * NN + p];
    keep_out[(size_t)b * NN + orig] =
        ((s_keep[p >> 6] >> (p & 63)) & 1) ? 1.0f : 0.0f;
  }
}

// Slow-but-correct fallback if d_ws can't hold the mask: classic iterative
// greedy NMS, one block per batch.
__global__ __launch_bounds__(1024) void nms_fallback(
    const float4* __restrict__ sbox, const u64* __restrict__ vbits,
    const int* __restrict__ order, float* __restrict__ keep_out) {
  int b = blockIdx.x, tid = threadIdx.x;
  __shared__ u64 dead[128];
  __shared__ int s_next;
  __shared__ float4 s_box;
  for (int w = tid; w < 128; w += 1024) dead[w] = ~vbits[b * 128 + w];
  for (int p = tid; p < NN; p += 1024)
    keep_out[(size_t)b * NN + order[(size_t)b * NN + p]] = 0.0f;
  __syncthreads();
  int i = 0;
  while (true) {
    if (tid == 0) {
      int nxt = NN;
      int w = i >> 6;
      u64 live = ~dead[w] & (~0ull << (i & 63));
      while (true) {
        if (live) { nxt = w * 64 + __builtin_ctzll(live); break; }
        if (++w >= 128) break;
        live = ~dead[w];
      }
      s_next = nxt;
      if (nxt < NN) {
        s_box = sbox[(size_t)b * NN + nxt];
        keep_out[(size_t)b * NN + order[(size_t)b * NN + nxt]] = 1.0f;
      }
    }
    __syncthreads();
    i = s_next;
    if (i >= NN) break;
    float4 kb = s_box;
    for (int j = i + 1 + tid; j < NN; j += 1024) {
      if (iou_pair(kb, sbox[(size_t)b * NN + j]) > 0.5f)
        atomicOr(&dead[j >> 6], 1ull << (j & 63));
    }
    __syncthreads();
    i = i + 1;
  }
}

extern "C" void kernel_launch(void* const* d_in, const int* in_sizes, int n_in,
                              void* d_out, int out_size, void* d_ws, size_t ws_size,
                              hipStream_t stream) {
  const float* logits = (const float*)d_in[0];
  const float4* deltas = (const float4*)d_in[1];
  const float4* anchors = (const float4*)d_in[2];
  float* out = (float*)d_out;
  float4* boxes_out = (float4*)(out + OFF_BOXES);
  float* scores_out = out + OFF_SCORES;
  float* labels_out = out + OFF_LABELS;
  float* keep_out = out + OFF_KEEP;
  float* all_out = out + OFF_ALL;

  char* ws = (char*)d_ws;
  u64* keys = (u64*)(ws + WS_KEYS);
  unsigned char* vbyte = (unsigned char*)(ws + WS_VBYTE);
  int* order = (int*)(ws + WS_ORDER);
  float4* sbox = (float4*)(ws + WS_SBOX);
  u64* vbits = (u64*)(ws + WS_VBITS);
  u64* mask = (u64*)(ws + WS_MASK);
  u64* dnm = (u64*)(ws + WS_DNM);
  int* part = (int*)(ws + WS_PART);

  decode_kernel<<<dim3(NB * NN / 4), dim3(256), 0, stream>>>(
      logits, deltas, anchors, boxes_out, scores_out, labels_out, all_out,
      keys, vbyte, vbits);
  if (ws_size >= WS_TOTAL) {
    rank_part_kernel<<<dim3(NN / 256, NSEG, NB), dim3(1024), 0, stream>>>(
        keys, part, dnm);
    rank_final_kernel<<<dim3(NN / 256, NB), dim3(256), 0, stream>>>(
        part, (const float4*)boxes_out, vbyte, order, sbox, vbits);
    build_kernel<<<dim3(128, 65, NB), dim3(64), 0, stream>>>(sbox, mask, dnm);
    reduce_kernel<<<dim3(NB), dim3(512), 0, stream>>>(mask, vbits, dnm, order,
                                                      keep_out);
  } else if (ws_size >= WS_TOTAL_OLD) {
    rank_kernel<<<dim3(NN / 256, NB), dim3(1024), 0, stream>>>(
        keys, (const float4*)boxes_out, vbyte, order, sbox, vbits, dnm);
    build_kernel<<<dim3(128, 65, NB), dim3(64), 0, stream>>>(sbox, mask, dnm);
    reduce_kernel<<<dim3(NB), dim3(512), 0, stream>>>(mask, vbits, dnm, order,
                                                      keep_out);
  } else {
    rank_kernel<<<dim3(NN / 256, NB), dim3(1024), 0, stream>>>(
        keys, (const float4*)boxes_out, vbyte, order, sbox, vbits, dnm);
    nms_fallback<<<dim3(NB), dim3(1024), 0, stream>>>(sbox, vbits, order,
                                                      keep_out);
  }
}

// Round 3
// 260.007 us; speedup vs baseline: 1.7518x; 1.0138x over previous
//
#include <hip/hip_runtime.h>

// Problem constants (fixed by reference): B=2, N=8192, C=80
constexpr int NB = 2;
constexpr int NN = 8192;
constexpr int NC = 80;
constexpr int ROWS = NN + 1;  // mask rows per batch; row NN unused (legacy pad)

// d_out layout (floats), in reference return order:
// boxes[B,N,4], max_scores[B,N], labels[B,N], keep[B,N], all_scores[B,N,C]
constexpr size_t OFF_BOXES  = 0;
constexpr size_t OFF_SCORES = (size_t)NB * NN * 4;
constexpr size_t OFF_LABELS = OFF_SCORES + (size_t)NB * NN;
constexpr size_t OFF_KEEP   = OFF_LABELS + (size_t)NB * NN;
constexpr size_t OFF_ALL    = OFF_KEEP + (size_t)NB * NN;

// d_ws layout
constexpr size_t WS_KEYS  = 0;                                   // B*N u64
constexpr size_t WS_VBYTE = WS_KEYS + (size_t)NB * NN * 8;       // B*N u8
constexpr size_t WS_ORDER = WS_VBYTE + (size_t)NB * NN;          // B*N i32
constexpr size_t WS_SBOX  = WS_ORDER + (size_t)NB * NN * 4;      // B*N float4
constexpr size_t WS_VBITS = WS_SBOX + (size_t)NB * NN * 16;      // B*128 u64
constexpr size_t WS_MASK  = WS_VBITS + (size_t)NB * 128 * 8;     // B*ROWS*128 u64
constexpr size_t WS_DNM   = WS_MASK + (size_t)NB * ROWS * 128 * 8; // B*128*4*64 u64
constexpr size_t WS_PART  = WS_DNM + (size_t)NB * 128 * 4 * 64 * 8; // B*8*N i32
constexpr size_t WS_TOTAL = WS_PART + (size_t)NB * 8 * NN * 4;
// Old (single-kernel-rank) total, for the fallback gate:
constexpr size_t WS_TOTAL_OLD = WS_PART;
constexpr int DNM_WORDS = NB * 128 * 4 * 64;  // 65536
constexpr int NSEG = 8;                       // rank column segments

typedef unsigned long long u64;

// lgkmcnt(0)-only barrier: keeps global loads in flight across it.
// simm16: vmcnt[3:0]=0xF, expcnt=7<<4, lgkmcnt=0<<8, vmcnt[5:4]=3<<14 -> 0xC07F
__device__ inline void lbar() {
  __builtin_amdgcn_s_waitcnt(0xc07f);
  __builtin_amdgcn_s_barrier();
}

__device__ inline u64 readlane64(u64 v, int src) {
  unsigned int lo = (unsigned int)__builtin_amdgcn_readlane((int)(unsigned int)v, src);
  unsigned int hi = (unsigned int)__builtin_amdgcn_readlane((int)(unsigned int)(v >> 32), src);
  return ((u64)hi << 32) | lo;
}

__device__ inline u64 readfirstlane64(u64 v) {
  unsigned int lo = (unsigned int)__builtin_amdgcn_readfirstlane((int)(unsigned int)v);
  unsigned int hi = (unsigned int)__builtin_amdgcn_readfirstlane((int)(unsigned int)(v >> 32));
  return ((u64)hi << 32) | lo;
}

// IoU exactly mirroring the numpy op order; contraction off so f32 rounding
// matches numpy bit-for-bit (keep bits tolerate no error). Note this formula
// is bit-exactly SYMMETRIC in (p,q): fmax/fmin/add are commutative, so the
// lower-triangle column masks equal the transposed upper-triangle rows.
__device__ inline float iou_pair(const float4 p, const float4 q) {
#pragma clang fp contract(off)
  float areaA = (p.z - p.x) * (p.w - p.y);
  float areaB = (q.z - q.x) * (q.w - q.y);
  float ix1 = fmaxf(p.x, q.x);
  float iy1 = fmaxf(p.y, q.y);
  float ix2 = fminf(p.z, q.z);
  float iy2 = fminf(p.w, q.w);
  float inter = fmaxf(ix2 - ix1, 0.0f) * fmaxf(iy2 - iy1, 0.0f);
  float uni = areaA + areaB - inter;
  return inter / fmaxf(uni, 1e-9f);
}

__device__ inline float clip01(float v) { return fminf(fmaxf(v, 0.0f), 1.0f); }

// One wave per (b,n): sigmoid all 80 classes, max/argmax (first-index ties),
// box decode, validity, sort key. Also zero-inits vbits.
__global__ __launch_bounds__(256) void decode_kernel(
    const float* __restrict__ logits, const float4* __restrict__ deltas,
    const float4* __restrict__ anchors, float4* __restrict__ boxes_out,
    float* __restrict__ scores_out, float* __restrict__ labels_out,
    float* __restrict__ all_out, u64* __restrict__ keys,
    unsigned char* __restrict__ vbyte, u64* __restrict__ vbits) {
#pragma clang fp contract(off)
  if (blockIdx.x == 0 && threadIdx.x < NB * 128) vbits[threadIdx.x] = 0ull;
  int wid = (blockIdx.x * 256 + threadIdx.x) >> 6;  // 0 .. B*N-1
  int lane = threadIdx.x & 63;
  int n = wid & (NN - 1);
  size_t base = (size_t)wid * NC;

  float x0 = logits[base + lane];
  float sig0 = 1.0f / (1.0f + expf(-x0));
  all_out[base + lane] = sig0;
  float bs = sig0;
  int bidx = lane;
  if (lane < NC - 64) {
    float x1 = logits[base + 64 + lane];
    float sig1 = 1.0f / (1.0f + expf(-x1));
    all_out[base + 64 + lane] = sig1;
    if (sig1 > bs) { bs = sig1; bidx = lane + 64; }  // tie -> smaller idx wins
  }
  for (int off = 32; off; off >>= 1) {
    float os = __shfl_xor(bs, off, 64);
    int oi = __shfl_xor(bidx, off, 64);
    if (os > bs || (os == bs && oi < bidx)) { bs = os; bidx = oi; }
  }
  if (lane == 0) {
    float4 d = deltas[wid];
    float4 a = anchors[n];
    float aw = a.z - a.x, ah = a.w - a.y;
    float acx = a.x + 0.5f * aw, acy = a.y + 0.5f * ah;
    float dw = fminf(d.z, 4.0f), dh = fminf(d.w, 4.0f);
    float pcx = d.x * aw + acx;
    float pcy = d.y * ah + acy;
    float pw = expf(dw) * aw;
    float ph = expf(dh) * ah;
    float4 bx;
    bx.x = clip01(pcx - 0.5f * pw);
    bx.y = clip01(pcy - 0.5f * ph);
    bx.z = clip01(pcx + 0.5f * pw);
    bx.w = clip01(pcy + 0.5f * ph);
    boxes_out[wid] = bx;
    scores_out[wid] = bs;
    labels_out[wid] = (float)bidx;
    float bw = bx.z - bx.x, bh = bx.w - bx.y;
    bool valid = (bs > 0.5f) && (bw > 0.01f) && (bh > 0.01f) &&
                 (bw < 0.99f) && (bh < 0.99f);
    vbyte[wid] = valid ? 1 : 0;
    // score bits monotone (score>0); tie-break: smaller n first under
    // DESCENDING key sort -> (N-1-n) in low bits. Keys are UNIQUE.
    keys[wid] = ((u64)__float_as_uint(bs) << 32) | (unsigned int)(NN - 1 - n);
  }
}

// Rank pass 1: partial counts over a column SEGMENT. Grid (32 rowblocks,
// NSEG colsegs, NB); block = 1024 threads = 256 rows x 4 quarters. The
// per-thread scalar-load chain is 8x shorter than the monolithic version
// and 8x more blocks occupy the chip. Column index is wave-uniform ->
// key loads scalarize. Also zero-inits dnm.
__global__ __launch_bounds__(1024) void rank_part_kernel(
    const u64* __restrict__ keys, int* __restrict__ part,
    u64* __restrict__ dnm) {
  int b = blockIdx.z, seg = blockIdx.y, rb = blockIdx.x;
  int gid = ((blockIdx.z * NSEG + blockIdx.y) * gridDim.x + blockIdx.x) * 1024 +
            threadIdx.x;
  if (gid < DNM_WORDS) dnm[gid] = 0ull;
  int r = threadIdx.x & 255;   // row slot
  int q = threadIdx.x >> 8;    // column quarter 0..3 (wave-uniform)
  int i = rb * 256 + r;
  const u64* kb = keys + (size_t)b * NN;
  u64 myk = kb[i];
  int cnt = 0;
  int j0 = seg * (NN / NSEG) + q * (NN / NSEG / 4);
  int j1 = j0 + NN / NSEG / 4;  // 256 iterations
#pragma unroll 8
  for (int j = j0; j < j1; ++j) {
    u64 kj = kb[j];  // wave-uniform address -> scalar load
    cnt += (kj > myk) ? 1 : 0;
  }
  __shared__ unsigned short partl[4][256];
  partl[q][r] = (unsigned short)cnt;
  __syncthreads();
  if (threadIdx.x < 256) {
    int s = partl[0][r] + partl[1][r] + partl[2][r] + partl[3][r];
    part[((size_t)b * NSEG + seg) * NN + i] = s;
  }
}

// Rank pass 2: rank_i = sum of segment partials (keys unique -> permutation);
// scatter order/sbox/vbits.
__global__ __launch_bounds__(256) void rank_final_kernel(
    const int* __restrict__ part, const float4* __restrict__ boxes,
    const unsigned char* __restrict__ vbyte, int* __restrict__ order,
    float4* __restrict__ sbox, u64* __restrict__ vbits) {
  int b = blockIdx.y;
  int i = blockIdx.x * 256 + threadIdx.x;
  const int* pb = part + (size_t)b * NSEG * NN + i;
  int rank = 0;
#pragma unroll
  for (int s = 0; s < NSEG; ++s) rank += pb[(size_t)s * NN];
  order[(size_t)b * NN + rank] = i;
  sbox[(size_t)b * NN + rank] = boxes[(size_t)b * NN + i];
  if (vbyte[(size_t)b * NN + i])
    atomicOr(&vbits[b * 128 + (rank >> 6)], 1ull << (rank & 63));
}

// Monolithic rank (fallback path only, when ws can't hold part[]).
__global__ __launch_bounds__(1024) void rank_kernel(
    const u64* __restrict__ keys, const float4* __restrict__ boxes,
    const unsigned char* __restrict__ vbyte, int* __restrict__ order,
    float4* __restrict__ sbox, u64* __restrict__ vbits,
    u64* __restrict__ dnm) {
  int b = blockIdx.y;
  int gid = (blockIdx.y * gridDim.x + blockIdx.x) * 1024 + threadIdx.x;
  for (int z = gid; z < DNM_WORDS; z += 65536) dnm[z] = 0ull;
  int r = threadIdx.x & 255;   // row slot
  int q = threadIdx.x >> 8;    // column quarter 0..3
  int i = blockIdx.x * 256 + r;
  const u64* kb = keys + (size_t)b * NN;
  u64 myk = kb[i];
  int cnt = 0;
  int j0 = q * (NN / 4), j1 = j0 + NN / 4;
#pragma unroll 8
  for (int j = j0; j < j1; ++j) {
    u64 kj = kb[j];  // wave-uniform address -> scalar load
    cnt += (kj > myk) ? 1 : 0;
  }
  __shared__ unsigned short part[4][256];
  part[q][r] = (unsigned short)cnt;
  __syncthreads();
  if (threadIdx.x < 256) {
    int rank = part[0][r] + part[1][r] + part[2][r] + part[3][r];
    order[(size_t)b * NN + rank] = i;
    sbox[(size_t)b * NN + rank] = boxes[(size_t)b * NN + i];
    if (vbyte[(size_t)b * NN + i])
      atomicOr(&vbits[b * 128 + (rank >> 6)], 1ull << (rank & 63));
  }
}

// 64x64 tile of the (sorted-order) suppression matrix. Triangular grid:
// (128, 65) blocks map bijectively onto the 8256 upper-triangle tiles.
// Diagonal tiles compute the FULL symmetric row: upper half to mask[],
// LOWER half to dnm slot 0 — the column mask ("who above me suppresses me")
// consumed by reduce's ballot fixpoint. Off-diag tiles with bx-by in {1..3}
// also write compact dnm.
__global__ __launch_bounds__(64) void build_kernel(
    const float4* __restrict__ sbox, u64* __restrict__ mask,
    u64* __restrict__ dnm) {
  int byq = blockIdx.y, bxq = blockIdx.x, b = blockIdx.z;
  int by, bx;
  if (bxq >= byq) {
    by = byq; bx = bxq;
  } else if (byq == 64) {
    return;  // 64 spare blocks in the triangular mapping
  } else {
    by = 128 - byq; bx = 127 - bxq;  // mirrored lower-left -> upper rows 65..127
  }
  int lane = threadIdx.x;
  __shared__ float4 cb[64];
  cb[lane] = sbox[(size_t)b * NN + bx * 64 + lane];
  __syncthreads();
  int i = by * 64 + lane;
  float4 rb = sbox[(size_t)b * NN + i];
  u64 word = 0;
  if (bx == by) {
    for (int jj = 0; jj < 64; ++jj)
      if (iou_pair(rb, cb[jj]) > 0.5f) word |= 1ull << jj;
    word &= ~(1ull << lane);  // clear self-IoU bit
    u64 lmask = (1ull << lane) - 1ull;
    mask[((size_t)b * ROWS + i) * 128 + bx] = word & ~lmask;
    dnm[(((size_t)b * 128 + by) * 4 + 0) * 64 + lane] = word & lmask;
  } else {
    for (int jj = 0; jj < 64; ++jj)
      if (iou_pair(rb, cb[jj]) > 0.5f) word |= 1ull << jj;
    mask[((size_t)b * ROWS + i) * 128 + bx] = word;
    int dq = bx - by;
    if (dq < 4) dnm[(((size_t)b * 128 + by) * 4 + dq) * 64 + lane] = word;
  }
}

struct TSet {
  ulonglong2 t0, t1, t2, t3, t4, t5, t6, t7, t8, t9;
};

// Greedy reduce v9: one 512-thread block per batch, one lgkm-only barrier
// per chunk; background pipeline has TWO chunks of load slack.
//  - Wave 0: in-chunk greedy via BALLOT FIXPOINT on lower-triangle column
//    masks (dnm slot 0); kept lanes deposit words c+1..c+3 via LDS atomicOr.
//  - Waves 1..7: at chunk c ISSUE rows of chunk c-1 (rowlist published at
//    c-1) into register set U/V; CONSUME the set issued at c-2 (rows of
//    chunk c-3) into words > c.
//  v9 load-volume fix: a set consumed at body cc only deposits words > cc,
//  so rows are loaded starting at even word s = (ci+3)&~1 (ci = issue body;
//  cc = ci+2 -> s = (cc+1)&~1, same value). Per-lane word = s + 2*lane with
//  bounds guards. Pad row slots (>= nk, rowlist value NN) are skipped via a
//  readfirstlane'd kept-count -> pad rows never loaded (zero row removed).
//  Cuts bg L2 volume ~2.5-3x (it was the per-CU L2-throughput bottleneck).
__global__ __launch_bounds__(512) void reduce_kernel(
    u64* __restrict__ mask, const u64* __restrict__ vbits,
    const u64* __restrict__ dnm, const int* __restrict__ order,
    float* __restrict__ keep_out) {
  int b = blockIdx.x, tid = threadIdx.x;
  int lane = tid & 63, wave = tid >> 6;
  __shared__ u64 s_remv[128];
  __shared__ u64 s_keep[128];
  __shared__ int s_rowlist[2][80];
  __shared__ int s_nk[2];
  const u64* mb = mask + (size_t)b * ROWS * 128;
  const u64* dn = dnm + (size_t)b * 128 * 4 * 64;

  for (int w = tid; w < 128; w += 512) s_remv[w] = 0ull;
  if (tid < 2) s_nk[tid] = 0;
  if (tid < 160) s_rowlist[tid / 80][tid % 80] = NN;

  // Wave 0 state: vbits in regs; 4 rotating prefetch slots of (d,n,m,o).
  u64 va = 0, vb2 = 0;
  u64 dA = 0, nA = 0, mA = 0, oA = 0, dB = 0, nB = 0, mB = 0, oB = 0;
  u64 dC = 0, nC = 0, mC = 0, oC = 0, dD = 0, nD = 0, mD = 0, oD = 0;
  if (wave == 0) {
    va = vbits[b * 128 + 2 * lane];
    vb2 = vbits[b * 128 + 2 * lane + 1];
    const u64* r0 = dn + lane;  // chunk 0
    dA = r0[0]; nA = r0[64]; mA = r0[128]; oA = r0[192];
    const u64* r1 = dn + 4 * 64 + lane;  // chunk 1
    dB = r1[0]; nB = r1[64]; mB = r1[128]; oB = r1[192];
  }
  TSet U{}, V{};  // background in-flight sets (even / odd bodies)
  int w0i = 2 * lane;
  __syncthreads();  // LDS init visible

  // Serial body for chunk c: use (dcur..ocur); prefetch chunk c+2 into the
  // (c+2)%4 slot (its previous value died at body c-2) -> no copies/selects.
  auto serial_body = [&](int c, u64 dcur, u64 ncur, u64 mcur, u64 ocur,
                         u64& dnew, u64& nnew, u64& mnew, u64& onew) {
    if (c + 2 < 128) {  // issue first, consume 2 chunks later
      const u64* rp = dn + (size_t)(c + 2) * 4 * 64 + lane;
      dnew = rp[0]; nnew = rp[64]; mnew = rp[128]; onew = rp[192];
    } else {
      dnew = 0; nnew = 0; mnew = 0; onew = 0;
    }
    int par = c & 1;
    u64 rm = s_remv[c];  // LDS broadcast read
    u64 vbw = readlane64(par ? vb2 : va, c >> 1);
    u64 cand = readfirstlane64(vbw & ~rm);  // uniform -> SGPR domain
    // Ballot fixpoint: dcur = lane's lower-triangle column mask.
    u64 kept = cand;
    while (true) {
      u64 sup = __ballot((dcur & kept) != 0ull);
      u64 nk = cand & ~sup;
      if (nk == kept) break;
      kept = nk;
    }
    bool isk = (kept >> lane) & 1;
    if (c + 1 < 128 && isk && ncur) atomicOr(&s_remv[c + 1], ncur);
    if (c + 2 < 128 && isk && mcur) atomicOr(&s_remv[c + 2], mcur);
    if (c + 3 < 128 && isk && ocur) atomicOr(&s_remv[c + 3], ocur);
    s_rowlist[par][lane] = NN;  // pad; kept positions overwrite below
    if (isk) {
      int pos = __popcll(kept & ((1ull << lane) - 1ull));
      s_rowlist[par][pos] = c * 64 + lane;
    }
    if (lane == 0) {
      s_keep[c] = kept;
      s_nk[par] = __popcll(kept);
    }
  };

  auto bg_body = [&](int c, TSet& T) {
    // consume T (rows of chunk c-3, issued at body c-2 with start word
    // sc = (c+1)&~1) into words > c
    u64 ax = T.t0.x | T.t1.x | T.t2.x | T.t3.x | T.t4.x | T.t5.x | T.t6.x |
             T.t7.x | T.t8.x | T.t9.x;
    u64 ay = T.t0.y | T.t1.y | T.t2.y | T.t3.y | T.t4.y | T.t5.y | T.t6.y |
             T.t7.y | T.t8.y | T.t9.y;
    int sc = (c + 1) & ~1;
    int wx = sc + w0i, wy = wx + 1;
    if (wx > c && wx < 128 && ax) atomicOr(&s_remv[wx], ax);
    if (wy > c && wy < 128 && ay) atomicOr(&s_remv[wy], ay);
    // issue loads for rows of chunk c-1 (consumed at body c+2, words > c+2)
    int nk1 = s_nk[(c - 1) & 1];  // c=0 -> slot 1 = 0
    nk1 = __builtin_amdgcn_readfirstlane(nk1);
    T = TSet{};
    int si = (c + 3) & ~1;      // first word needed at consume
    int w = si + w0i;           // this lane's word pair base
    if (nk1 > 0 && w < 128) {
      const int* rl = s_rowlist[(c - 1) & 1];
      int base = wave - 1;  // waves 1..7 -> 0..6; stride 7 covers 0..69
      const u64* mw = mb + w;
      if (base < nk1)      T.t0 = *(const ulonglong2*)(mw + (size_t)rl[base] * 128);
      if (base + 7 < nk1)  T.t1 = *(const ulonglong2*)(mw + (size_t)rl[base + 7] * 128);
      if (base + 14 < nk1) T.t2 = *(const ulonglong2*)(mw + (size_t)rl[base + 14] * 128);
      if (base + 21 < nk1) T.t3 = *(const ulonglong2*)(mw + (size_t)rl[base + 21] * 128);
      if (base + 28 < nk1) T.t4 = *(const ulonglong2*)(mw + (size_t)rl[base + 28] * 128);
      if (base + 35 < nk1) T.t5 = *(const ulonglong2*)(mw + (size_t)rl[base + 35] * 128);
      if (base + 42 < nk1) T.t6 = *(const ulonglong2*)(mw + (size_t)rl[base + 42] * 128);
      if (base + 49 < nk1) T.t7 = *(const ulonglong2*)(mw + (size_t)rl[base + 49] * 128);
      if (base + 56 < nk1) T.t8 = *(const ulonglong2*)(mw + (size_t)rl[base + 56] * 128);
      if (base + 63 < nk1) T.t9 = *(const ulonglong2*)(mw + (size_t)rl[base + 63] * 128);
    }
  };

  for (int c = 0; c < 128; c += 4) {
    if (wave == 0) serial_body(c, dA, nA, mA, oA, dC, nC, mC, oC);
    else bg_body(c, U);
    lbar();
    if (wave == 0) serial_body(c + 1, dB, nB, mB, oB, dD, nD, mD, oD);
    else bg_body(c + 1, V);
    lbar();
    if (wave == 0) serial_body(c + 2, dC, nC, mC, oC, dA, nA, mA, oA);
    else bg_body(c + 2, U);
    lbar();
    if (wave == 0) serial_body(c + 3, dD, nD, mD, oD, dB, nB, mB, oB);
    else bg_body(c + 3, V);
    lbar();
  }

  // scatter keep flags back to original anchor order
  for (int p = tid; p < NN; p += 512) {
    int orig = order[(size_t)b * NN + p];
    keep_out[(size_t)b * NN + orig] =
        ((s_keep[p >> 6] >> (p & 63)) & 1) ? 1.0f : 0.0f;
  }
}

// Slow-but-correct fallback if d_ws can't hold the mask: classic iterative
// greedy NMS, one block per batch.
__global__ __launch_bounds__(1024) void nms_fallback(
    const float4* __restrict__ sbox, const u64* __restrict__ vbits,
    const int* __restrict__ order, float* __restrict__ keep_out) {
  int b = blockIdx.x, tid = threadIdx.x;
  __shared__ u64 dead[128];
  __shared__ int s_next;
  __shared__ float4 s_box;
  for (int w = tid; w < 128; w += 1024) dead[w] = ~vbits[b * 128 + w];
  for (int p = tid; p < NN; p += 1024)
    keep_out[(size_t)b * NN + order[(size_t)b * NN + p]] = 0.0f;
  __syncthreads();
  int i = 0;
  while (true) {
    if (tid == 0) {
      int nxt = NN;
      int w = i >> 6;
      u64 live = ~dead[w] & (~0ull << (i & 63));
      while (true) {
        if (live) { nxt = w * 64 + __builtin_ctzll(live); break; }
        if (++w >= 128) break;
        live = ~dead[w];
      }
      s_next = nxt;
      if (nxt < NN) {
        s_box = sbox[(size_t)b * NN + nxt];
        keep_out[(size_t)b * NN + order[(size_t)b * NN + nxt]] = 1.0f;
      }
    }
    __syncthreads();
    i = s_next;
    if (i >= NN) break;
    float4 kb = s_box;
    for (int j = i + 1 + tid; j < NN; j += 1024) {
      if (iou_pair(kb, sbox[(size_t)b * NN + j]) > 0.5f)
        atomicOr(&dead[j >> 6], 1ull << (j & 63));
    }
    __syncthreads();
    i = i + 1;
  }
}

extern "C" void kernel_launch(void* const* d_in, const int* in_sizes, int n_in,
                              void* d_out, int out_size, void* d_ws, size_t ws_size,
                              hipStream_t stream) {
  const float* logits = (const float*)d_in[0];
  const float4* deltas = (const float4*)d_in[1];
  const float4* anchors = (const float4*)d_in[2];
  float* out = (float*)d_out;
  float4* boxes_out = (float4*)(out + OFF_BOXES);
  float* scores_out = out + OFF_SCORES;
  float* labels_out = out + OFF_LABELS;
  float* keep_out = out + OFF_KEEP;
  float* all_out = out + OFF_ALL;

  char* ws = (char*)d_ws;
  u64* keys = (u64*)(ws + WS_KEYS);
  unsigned char* vbyte = (unsigned char*)(ws + WS_VBYTE);
  int* order = (int*)(ws + WS_ORDER);
  float4* sbox = (float4*)(ws + WS_SBOX);
  u64* vbits = (u64*)(ws + WS_VBITS);
  u64* mask = (u64*)(ws + WS_MASK);
  u64* dnm = (u64*)(ws + WS_DNM);
  int* part = (int*)(ws + WS_PART);

  decode_kernel<<<dim3(NB * NN / 4), dim3(256), 0, stream>>>(
      logits, deltas, anchors, boxes_out, scores_out, labels_out, all_out,
      keys, vbyte, vbits);
  if (ws_size >= WS_TOTAL) {
    rank_part_kernel<<<dim3(NN / 256, NSEG, NB), dim3(1024), 0, stream>>>(
        keys, part, dnm);
    rank_final_kernel<<<dim3(NN / 256, NB), dim3(256), 0, stream>>>(
        part, (const float4*)boxes_out, vbyte, order, sbox, vbits);
    build_kernel<<<dim3(128, 65, NB), dim3(64), 0, stream>>>(sbox, mask, dnm);
    reduce_kernel<<<dim3(NB), dim3(512), 0, stream>>>(mask, vbits, dnm, order,
                                                      keep_out);
  } else if (ws_size >= WS_TOTAL_OLD) {
    rank_kernel<<<dim3(NN / 256, NB), dim3(1024), 0, stream>>>(
        keys, (const float4*)boxes_out, vbyte, order, sbox, vbits, dnm);
    build_kernel<<<dim3(128, 65, NB), dim3(64), 0, stream>>>(sbox, mask, dnm);
    reduce_kernel<<<dim3(NB), dim3(512), 0, stream>>>(mask, vbits, dnm, order,
                                                      keep_out);
  } else {
    rank_kernel<<<dim3(NN / 256, NB), dim3(1024), 0, stream>>>(
        keys, (const float4*)boxes_out, vbyte, order, sbox, vbits, dnm);
    nms_fallback<<<dim3(NB), dim3(1024), 0, stream>>>(sbox, vbits, order,
                                                      keep_out);
  }
}

// Round 4
// 247.995 us; speedup vs baseline: 1.8366x; 1.0484x over previous
//
#include <hip/hip_runtime.h>

// Problem constants (fixed by reference): B=2, N=8192, C=80
constexpr int NB = 2;
constexpr int NN = 8192;
constexpr int NC = 80;
constexpr int ROWS = NN + 1;  // mask rows per batch; row NN is an all-zero row

// d_out layout (floats), in reference return order:
// boxes[B,N,4], max_scores[B,N], labels[B,N], keep[B,N], all_scores[B,N,C]
constexpr size_t OFF_BOXES  = 0;
constexpr size_t OFF_SCORES = (size_t)NB * NN * 4;
constexpr size_t OFF_LABELS = OFF_SCORES + (size_t)NB * NN;
constexpr size_t OFF_KEEP   = OFF_LABELS + (size_t)NB * NN;
constexpr size_t OFF_ALL    = OFF_KEEP + (size_t)NB * NN;

// d_ws layout
constexpr size_t WS_KEYS  = 0;                                   // B*N u64
constexpr size_t WS_VBYTE = WS_KEYS + (size_t)NB * NN * 8;       // B*N u8
constexpr size_t WS_ORDER = WS_VBYTE + (size_t)NB * NN;          // B*N i32
constexpr size_t WS_SBOX  = WS_ORDER + (size_t)NB * NN * 4;      // B*N float4
constexpr size_t WS_VBITS = WS_SBOX + (size_t)NB * NN * 16;      // B*128 u64
constexpr size_t WS_MASK  = WS_VBITS + (size_t)NB * 128 * 8;     // B*ROWS*128 u64
constexpr size_t WS_DNM   = WS_MASK + (size_t)NB * ROWS * 128 * 8; // B*128*4*64 u64
constexpr size_t WS_PART  = WS_DNM + (size_t)NB * 128 * 4 * 64 * 8; // B*8*N i32
constexpr size_t WS_TOTAL = WS_PART + (size_t)NB * 8 * NN * 4;
// Old (single-kernel-rank) total, for the fallback gate:
constexpr size_t WS_TOTAL_OLD = WS_PART;
constexpr int DNM_WORDS = NB * 128 * 4 * 64;  // 65536
constexpr int NSEG = 8;                       // rank column segments

typedef unsigned long long u64;

// lgkmcnt(0)-only barrier: keeps global loads in flight across it.
// simm16: vmcnt[3:0]=0xF, expcnt=7<<4, lgkmcnt=0<<8, vmcnt[5:4]=3<<14 -> 0xC07F
__device__ inline void lbar() {
  __builtin_amdgcn_s_waitcnt(0xc07f);
  __builtin_amdgcn_s_barrier();
}

__device__ inline u64 readlane64(u64 v, int src) {
  unsigned int lo = (unsigned int)__builtin_amdgcn_readlane((int)(unsigned int)v, src);
  unsigned int hi = (unsigned int)__builtin_amdgcn_readlane((int)(unsigned int)(v >> 32), src);
  return ((u64)hi << 32) | lo;
}

__device__ inline u64 readfirstlane64(u64 v) {
  unsigned int lo = (unsigned int)__builtin_amdgcn_readfirstlane((int)(unsigned int)v);
  unsigned int hi = (unsigned int)__builtin_amdgcn_readfirstlane((int)(unsigned int)(v >> 32));
  return ((u64)hi << 32) | lo;
}

// IoU exactly mirroring the numpy op order; contraction off so f32 rounding
// matches numpy bit-for-bit (keep bits tolerate no error). Note this formula
// is bit-exactly SYMMETRIC in (p,q): fmax/fmin/add are commutative, so the
// lower-triangle column masks equal the transposed upper-triangle rows.
__device__ inline float iou_pair(const float4 p, const float4 q) {
#pragma clang fp contract(off)
  float areaA = (p.z - p.x) * (p.w - p.y);
  float areaB = (q.z - q.x) * (q.w - q.y);
  float ix1 = fmaxf(p.x, q.x);
  float iy1 = fmaxf(p.y, q.y);
  float ix2 = fminf(p.z, q.z);
  float iy2 = fminf(p.w, q.w);
  float inter = fmaxf(ix2 - ix1, 0.0f) * fmaxf(iy2 - iy1, 0.0f);
  float uni = areaA + areaB - inter;
  return inter / fmaxf(uni, 1e-9f);
}

__device__ inline float clip01(float v) { return fminf(fmaxf(v, 0.0f), 1.0f); }

// One wave per (b,n): sigmoid all 80 classes, max/argmax (first-index ties),
// box decode, validity, sort key. Also zero-inits vbits.
__global__ __launch_bounds__(256) void decode_kernel(
    const float* __restrict__ logits, const float4* __restrict__ deltas,
    const float4* __restrict__ anchors, float4* __restrict__ boxes_out,
    float* __restrict__ scores_out, float* __restrict__ labels_out,
    float* __restrict__ all_out, u64* __restrict__ keys,
    unsigned char* __restrict__ vbyte, u64* __restrict__ vbits) {
#pragma clang fp contract(off)
  if (blockIdx.x == 0 && threadIdx.x < NB * 128) vbits[threadIdx.x] = 0ull;
  int wid = (blockIdx.x * 256 + threadIdx.x) >> 6;  // 0 .. B*N-1
  int lane = threadIdx.x & 63;
  int n = wid & (NN - 1);
  size_t base = (size_t)wid * NC;

  float x0 = logits[base + lane];
  float sig0 = 1.0f / (1.0f + expf(-x0));
  all_out[base + lane] = sig0;
  float bs = sig0;
  int bidx = lane;
  if (lane < NC - 64) {
    float x1 = logits[base + 64 + lane];
    float sig1 = 1.0f / (1.0f + expf(-x1));
    all_out[base + 64 + lane] = sig1;
    if (sig1 > bs) { bs = sig1; bidx = lane + 64; }  // tie -> smaller idx wins
  }
  for (int off = 32; off; off >>= 1) {
    float os = __shfl_xor(bs, off, 64);
    int oi = __shfl_xor(bidx, off, 64);
    if (os > bs || (os == bs && oi < bidx)) { bs = os; bidx = oi; }
  }
  if (lane == 0) {
    float4 d = deltas[wid];
    float4 a = anchors[n];
    float aw = a.z - a.x, ah = a.w - a.y;
    float acx = a.x + 0.5f * aw, acy = a.y + 0.5f * ah;
    float dw = fminf(d.z, 4.0f), dh = fminf(d.w, 4.0f);
    float pcx = d.x * aw + acx;
    float pcy = d.y * ah + acy;
    float pw = expf(dw) * aw;
    float ph = expf(dh) * ah;
    float4 bx;
    bx.x = clip01(pcx - 0.5f * pw);
    bx.y = clip01(pcy - 0.5f * ph);
    bx.z = clip01(pcx + 0.5f * pw);
    bx.w = clip01(pcy + 0.5f * ph);
    boxes_out[wid] = bx;
    scores_out[wid] = bs;
    labels_out[wid] = (float)bidx;
    float bw = bx.z - bx.x, bh = bx.w - bx.y;
    bool valid = (bs > 0.5f) && (bw > 0.01f) && (bh > 0.01f) &&
                 (bw < 0.99f) && (bh < 0.99f);
    vbyte[wid] = valid ? 1 : 0;
    // score bits monotone (score>0); tie-break: smaller n first under
    // DESCENDING key sort -> (N-1-n) in low bits. Keys are UNIQUE.
    keys[wid] = ((u64)__float_as_uint(bs) << 32) | (unsigned int)(NN - 1 - n);
  }
}

// Rank pass 1: partial counts over a column SEGMENT. Grid (32 rowblocks,
// NSEG colsegs, NB); block = 1024 threads = 256 rows x 4 quarters. The
// per-thread scalar-load chain is 8x shorter than the monolithic version
// and 8x more blocks occupy the chip. Column index is wave-uniform ->
// key loads scalarize. Also zero-inits dnm.
__global__ __launch_bounds__(1024) void rank_part_kernel(
    const u64* __restrict__ keys, int* __restrict__ part,
    u64* __restrict__ dnm) {
  int b = blockIdx.z, seg = blockIdx.y, rb = blockIdx.x;
  int gid = ((blockIdx.z * NSEG + blockIdx.y) * gridDim.x + blockIdx.x) * 1024 +
            threadIdx.x;
  if (gid < DNM_WORDS) dnm[gid] = 0ull;
  int r = threadIdx.x & 255;   // row slot
  int q = threadIdx.x >> 8;    // column quarter 0..3 (wave-uniform)
  int i = rb * 256 + r;
  const u64* kb = keys + (size_t)b * NN;
  u64 myk = kb[i];
  int cnt = 0;
  int j0 = seg * (NN / NSEG) + q * (NN / NSEG / 4);
  int j1 = j0 + NN / NSEG / 4;  // 256 iterations
#pragma unroll 8
  for (int j = j0; j < j1; ++j) {
    u64 kj = kb[j];  // wave-uniform address -> scalar load
    cnt += (kj > myk) ? 1 : 0;
  }
  __shared__ unsigned short partl[4][256];
  partl[q][r] = (unsigned short)cnt;
  __syncthreads();
  if (threadIdx.x < 256) {
    int s = partl[0][r] + partl[1][r] + partl[2][r] + partl[3][r];
    part[((size_t)b * NSEG + seg) * NN + i] = s;
  }
}

// Rank pass 2: rank_i = sum of segment partials (keys unique -> permutation);
// scatter order/sbox/vbits.
__global__ __launch_bounds__(256) void rank_final_kernel(
    const int* __restrict__ part, const float4* __restrict__ boxes,
    const unsigned char* __restrict__ vbyte, int* __restrict__ order,
    float4* __restrict__ sbox, u64* __restrict__ vbits) {
  int b = blockIdx.y;
  int i = blockIdx.x * 256 + threadIdx.x;
  const int* pb = part + (size_t)b * NSEG * NN + i;
  int rank = 0;
#pragma unroll
  for (int s = 0; s < NSEG; ++s) rank += pb[(size_t)s * NN];
  order[(size_t)b * NN + rank] = i;
  sbox[(size_t)b * NN + rank] = boxes[(size_t)b * NN + i];
  if (vbyte[(size_t)b * NN + i])
    atomicOr(&vbits[b * 128 + (rank >> 6)], 1ull << (rank & 63));
}

// Monolithic rank (fallback path only, when ws can't hold part[]).
__global__ __launch_bounds__(1024) void rank_kernel(
    const u64* __restrict__ keys, const float4* __restrict__ boxes,
    const unsigned char* __restrict__ vbyte, int* __restrict__ order,
    float4* __restrict__ sbox, u64* __restrict__ vbits,
    u64* __restrict__ dnm) {
  int b = blockIdx.y;
  int gid = (blockIdx.y * gridDim.x + blockIdx.x) * 1024 + threadIdx.x;
  for (int z = gid; z < DNM_WORDS; z += 65536) dnm[z] = 0ull;
  int r = threadIdx.x & 255;   // row slot
  int q = threadIdx.x >> 8;    // column quarter 0..3
  int i = blockIdx.x * 256 + r;
  const u64* kb = keys + (size_t)b * NN;
  u64 myk = kb[i];
  int cnt = 0;
  int j0 = q * (NN / 4), j1 = j0 + NN / 4;
#pragma unroll 8
  for (int j = j0; j < j1; ++j) {
    u64 kj = kb[j];  // wave-uniform address -> scalar load
    cnt += (kj > myk) ? 1 : 0;
  }
  __shared__ unsigned short part[4][256];
  part[q][r] = (unsigned short)cnt;
  __syncthreads();
  if (threadIdx.x < 256) {
    int rank = part[0][r] + part[1][r] + part[2][r] + part[3][r];
    order[(size_t)b * NN + rank] = i;
    sbox[(size_t)b * NN + rank] = boxes[(size_t)b * NN + i];
    if (vbyte[(size_t)b * NN + i])
      atomicOr(&vbits[b * 128 + (rank >> 6)], 1ull << (rank & 63));
  }
}

// 64x64 tile of the (sorted-order) suppression matrix. Triangular grid:
// (128, 65) blocks map bijectively onto the 8256 upper-triangle tiles.
// Diagonal tiles compute the FULL symmetric row: upper half to mask[],
// LOWER half to dnm slot 0 — the column mask ("who above me suppresses me")
// consumed by reduce's ballot fixpoint. Off-diag tiles with bx-by in {1..3}
// also write compact dnm.
__global__ __launch_bounds__(64) void build_kernel(
    const float4* __restrict__ sbox, u64* __restrict__ mask,
    u64* __restrict__ dnm) {
  int byq = blockIdx.y, bxq = blockIdx.x, b = blockIdx.z;
  int by, bx;
  if (bxq >= byq) {
    by = byq; bx = bxq;
  } else if (byq == 64) {
    return;  // 64 spare blocks in the triangular mapping
  } else {
    by = 128 - byq; bx = 127 - bxq;  // mirrored lower-left -> upper rows 65..127
  }
  int lane = threadIdx.x;
  __shared__ float4 cb[64];
  cb[lane] = sbox[(size_t)b * NN + bx * 64 + lane];
  __syncthreads();
  int i = by * 64 + lane;
  float4 rb = sbox[(size_t)b * NN + i];
  u64 word = 0;
  if (bx == by) {
    for (int jj = 0; jj < 64; ++jj)
      if (iou_pair(rb, cb[jj]) > 0.5f) word |= 1ull << jj;
    word &= ~(1ull << lane);  // clear self-IoU bit
    u64 lmask = (1ull << lane) - 1ull;
    mask[((size_t)b * ROWS + i) * 128 + bx] = word & ~lmask;
    dnm[(((size_t)b * 128 + by) * 4 + 0) * 64 + lane] = word & lmask;
  } else {
    for (int jj = 0; jj < 64; ++jj)
      if (iou_pair(rb, cb[jj]) > 0.5f) word |= 1ull << jj;
    mask[((size_t)b * ROWS + i) * 128 + bx] = word;
    int dq = bx - by;
    if (dq < 4) dnm[(((size_t)b * 128 + by) * 4 + dq) * 64 + lane] = word;
  }
}

struct TSet {
  ulonglong2 t0, t1, t2, t3, t4, t5, t6, t7, t8, t9;
};

// Greedy reduce v10: one 512-thread block per batch, one lgkm-only barrier
// per chunk; background pipeline has TWO chunks of load slack.
//  - Wave 0: in-chunk greedy via BALLOT FIXPOINT on lower-triangle column
//    masks (dnm slot 0); kept lanes deposit words c+1..c+3 via LDS atomicOr.
//  - Waves 1..7: at chunk c ISSUE rows of chunk c-1 (rowlist published at
//    c-1) into register set U/V; CONSUME the set issued at c-2 (rows of
//    chunk c-3) into words > c.
//  v10 fix: ALL main-loop global loads are UNCONDITIONAL so the number of
//  outstanding VMEM ops is statically known and the compiler can emit
//  COUNTED s_waitcnt vmcnt(N) at the consume (waiting only the 2-body-old
//  set). v8/v9's runtime-conditional loads forced conservative vmcnt(0),
//  exposing a full L3/cross-XCD latency (~600-900 cy) on EVERY body.
//   - pad rowlist slots (value NN) load the all-zero mask row (restored);
//   - per-lane word index clamped to 126 when >=128 (garbage discarded by
//     the existing wx<128 deposit guard);
//   - wave-0 dnm prefetch chunk index clamped to 127 (slots for c+2>=128
//     are never consumed);
//   - s_nk removed (no longer needed -> one fewer LDS round-trip in bg).
__global__ __launch_bounds__(512) void reduce_kernel(
    u64* __restrict__ mask, const u64* __restrict__ vbits,
    const u64* __restrict__ dnm, const int* __restrict__ order,
    float* __restrict__ keep_out) {
  int b = blockIdx.x, tid = threadIdx.x;
  int lane = tid & 63, wave = tid >> 6;
  __shared__ u64 s_remv[128];
  __shared__ u64 s_keep[128];
  __shared__ int s_rowlist[2][80];
  u64* mbz = mask + (size_t)b * ROWS * 128;
  const u64* mb = mbz;
  const u64* dn = dnm + (size_t)b * 128 * 4 * 64;

  for (int w = tid; w < 128; w += 512) {
    s_remv[w] = 0ull;
    mbz[(size_t)NN * 128 + w] = 0ull;  // zero row (pad rowlist target)
  }
  if (tid < 160) s_rowlist[tid / 80][tid % 80] = NN;

  // Wave 0 state: vbits in regs; 4 rotating prefetch slots of (d,n,m,o).
  u64 va = 0, vb2 = 0;
  u64 dA = 0, nA = 0, mA = 0, oA = 0, dB = 0, nB = 0, mB = 0, oB = 0;
  u64 dC = 0, nC = 0, mC = 0, oC = 0, dD = 0, nD = 0, mD = 0, oD = 0;
  if (wave == 0) {
    va = vbits[b * 128 + 2 * lane];
    vb2 = vbits[b * 128 + 2 * lane + 1];
    const u64* r0 = dn + lane;  // chunk 0
    dA = r0[0]; nA = r0[64]; mA = r0[128]; oA = r0[192];
    const u64* r1 = dn + 4 * 64 + lane;  // chunk 1
    dB = r1[0]; nB = r1[64]; mB = r1[128]; oB = r1[192];
  }
  TSet U{}, V{};  // background in-flight sets (even / odd bodies)
  int w0i = 2 * lane;
  __syncthreads();  // full barrier: zero-row global write + LDS init visible

  // Serial body for chunk c: use (dcur..ocur); prefetch chunk c+2 into the
  // (c+2)%4 slot (its previous value died at body c-2) -> no copies/selects.
  auto serial_body = [&](int c, u64 dcur, u64 ncur, u64 mcur, u64 ocur,
                         u64& dnew, u64& nnew, u64& mnew, u64& onew) {
    {
      // Unconditional prefetch (clamped): slots for cp beyond the loop are
      // never consumed, so the clamped re-load of chunk 127 is harmless.
      int cp = (c + 2 < 128) ? (c + 2) : 127;
      const u64* rp = dn + (size_t)cp * 4 * 64 + lane;
      dnew = rp[0]; nnew = rp[64]; mnew = rp[128]; onew = rp[192];
    }
    int par = c & 1;
    u64 rm = s_remv[c];  // LDS broadcast read
    u64 vbw = readlane64(par ? vb2 : va, c >> 1);
    u64 cand = readfirstlane64(vbw & ~rm);  // uniform -> SGPR domain
    // Ballot fixpoint: dcur = lane's lower-triangle column mask.
    u64 kept = cand;
    while (true) {
      u64 sup = __ballot((dcur & kept) != 0ull);
      u64 nk = cand & ~sup;
      if (nk == kept) break;
      kept = nk;
    }
    bool isk = (kept >> lane) & 1;
    if (c + 1 < 128 && isk && ncur) atomicOr(&s_remv[c + 1], ncur);
    if (c + 2 < 128 && isk && mcur) atomicOr(&s_remv[c + 2], mcur);
    if (c + 3 < 128 && isk && ocur) atomicOr(&s_remv[c + 3], ocur);
    s_rowlist[par][lane] = NN;  // pad; kept positions overwrite below
    if (isk) {
      int pos = __popcll(kept & ((1ull << lane) - 1ull));
      s_rowlist[par][pos] = c * 64 + lane;
    }
    if (lane == 0) s_keep[c] = kept;
  };

  auto bg_body = [&](int c, TSet& T) {
    // consume T (rows of chunk c-3, issued at body c-2 with start word
    // sc = (c+1)&~1) into words > c. Pad-row loads returned the zero row;
    // clamped-word lanes are discarded by the wx/wy < 128 guards.
    u64 ax = T.t0.x | T.t1.x | T.t2.x | T.t3.x | T.t4.x | T.t5.x | T.t6.x |
             T.t7.x | T.t8.x | T.t9.x;
    u64 ay = T.t0.y | T.t1.y | T.t2.y | T.t3.y | T.t4.y | T.t5.y | T.t6.y |
             T.t7.y | T.t8.y | T.t9.y;
    int sc = (c + 1) & ~1;
    int wx = sc + w0i, wy = wx + 1;
    if (wx > c && wx < 128 && ax) atomicOr(&s_remv[wx], ax);
    if (wy > c && wy < 128 && ay) atomicOr(&s_remv[wy], ay);
    // Issue loads for rows of chunk c-1 (consumed at body c+2, words > c+2).
    // ALL 10 loads unconditional -> static vmcnt at the consume.
    const int* rl = s_rowlist[(c - 1) & 1];
    int base = wave - 1;  // waves 1..7 -> 0..6; stride 7 covers 0..69
    int si = (c + 3) & ~1;      // first word needed at consume
    int w = si + w0i;           // this lane's word pair base
    if (w > 126) w = 126;       // clamp: load valid memory; discarded later
    const u64* mw = mb + w;
    T.t0 = *(const ulonglong2*)(mw + (size_t)rl[base] * 128);
    T.t1 = *(const ulonglong2*)(mw + (size_t)rl[base + 7] * 128);
    T.t2 = *(const ulonglong2*)(mw + (size_t)rl[base + 14] * 128);
    T.t3 = *(const ulonglong2*)(mw + (size_t)rl[base + 21] * 128);
    T.t4 = *(const ulonglong2*)(mw + (size_t)rl[base + 28] * 128);
    T.t5 = *(const ulonglong2*)(mw + (size_t)rl[base + 35] * 128);
    T.t6 = *(const ulonglong2*)(mw + (size_t)rl[base + 42] * 128);
    T.t7 = *(const ulonglong2*)(mw + (size_t)rl[base + 49] * 128);
    T.t8 = *(const ulonglong2*)(mw + (size_t)rl[base + 56] * 128);
    T.t9 = *(const ulonglong2*)(mw + (size_t)rl[base + 63] * 128);
  };

  for (int c = 0; c < 128; c += 4) {
    if (wave == 0) serial_body(c, dA, nA, mA, oA, dC, nC, mC, oC);
    else bg_body(c, U);
    lbar();
    if (wave == 0) serial_body(c + 1, dB, nB, mB, oB, dD, nD, mD, oD);
    else bg_body(c + 1, V);
    lbar();
    if (wave == 0) serial_body(c + 2, dC, nC, mC, oC, dA, nA, mA, oA);
    else bg_body(c + 2, U);
    lbar();
    if (wave == 0) serial_body(c + 3, dD, nD, mD, oD, dB, nB, mB, oB);
    else bg_body(c + 3, V);
    lbar();
  }

  // scatter keep flags back to original anchor order
  for (int p = tid; p < NN; p += 512) {
    int orig = order[(size_t)b * NN + p];
    keep_out[(size_t)b * NN + orig] =
        ((s_keep[p >> 6] >> (p & 63)) & 1) ? 1.0f : 0.0f;
  }
}

// Slow-but-correct fallback if d_ws can't hold the mask: classic iterative
// greedy NMS, one block per batch.
__global__ __launch_bounds__(1024) void nms_fallback(
    const float4* __restrict__ sbox, const u64* __restrict__ vbits,
    const int* __restrict__ order, float* __restrict__ keep_out) {
  int b = blockIdx.x, tid = threadIdx.x;
  __shared__ u64 dead[128];
  __shared__ int s_next;
  __shared__ float4 s_box;
  for (int w = tid; w < 128; w += 1024) dead[w] = ~vbits[b * 128 + w];
  for (int p = tid; p < NN; p += 1024)
    keep_out[(size_t)b * NN + order[(size_t)b * NN + p]] = 0.0f;
  __syncthreads();
  int i = 0;
  while (true) {
    if (tid == 0) {
      int nxt = NN;
      int w = i >> 6;
      u64 live = ~dead[w] & (~0ull << (i & 63));
      while (true) {
        if (live) { nxt = w * 64 + __builtin_ctzll(live); break; }
        if (++w >= 128) break;
        live = ~dead[w];
      }
      s_next = nxt;
      if (nxt < NN) {
        s_box = sbox[(size_t)b * NN + nxt];
        keep_out[(size_t)b * NN + order[(size_t)b * NN + nxt]] = 1.0f;
      }
    }
    __syncthreads();
    i = s_next;
    if (i >= NN) break;
    float4 kb = s_box;
    for (int j = i + 1 + tid; j < NN; j += 1024) {
      if (iou_pair(kb, sbox[(size_t)b * NN + j]) > 0.5f)
        atomicOr(&dead[j >> 6], 1ull << (j & 63));
    }
    __syncthreads();
    i = i + 1;
  }
}

extern "C" void kernel_launch(void* const* d_in, const int* in_sizes, int n_in,
                              void* d_out, int out_size, void* d_ws, size_t ws_size,
                              hipStream_t stream) {
  const float* logits = (const float*)d_in[0];
  const float4* deltas = (const float4*)d_in[1];
  const float4* anchors = (const float4*)d_in[2];
  float* out = (float*)d_out;
  float4* boxes_out = (float4*)(out + OFF_BOXES);
  float* scores_out = out + OFF_SCORES;
  float* labels_out = out + OFF_LABELS;
  float* keep_out = out + OFF_KEEP;
  float* all_out = out + OFF_ALL;

  char* ws = (char*)d_ws;
  u64* keys = (u64*)(ws + WS_KEYS);
  unsigned char* vbyte = (unsigned char*)(ws + WS_VBYTE);
  int* order = (int*)(ws + WS_ORDER);
  float4* sbox = (float4*)(ws + WS_SBOX);
  u64* vbits = (u64*)(ws + WS_VBITS);
  u64* mask = (u64*)(ws + WS_MASK);
  u64* dnm = (u64*)(ws + WS_DNM);
  int* part = (int*)(ws + WS_PART);

  decode_kernel<<<dim3(NB * NN / 4), dim3(256), 0, stream>>>(
      logits, deltas, anchors, boxes_out, scores_out, labels_out, all_out,
      keys, vbyte, vbits);
  if (ws_size >= WS_TOTAL) {
    rank_part_kernel<<<dim3(NN / 256, NSEG, NB), dim3(1024), 0, stream>>>(
        keys, part, dnm);
    rank_final_kernel<<<dim3(NN / 256, NB), dim3(256), 0, stream>>>(
        part, (const float4*)boxes_out, vbyte, order, sbox, vbits);
    build_kernel<<<dim3(128, 65, NB), dim3(64), 0, stream>>>(sbox, mask, dnm);
    reduce_kernel<<<dim3(NB), dim3(512), 0, stream>>>(mask, vbits, dnm, order,
                                                      keep_out);
  } else if (ws_size >= WS_TOTAL_OLD) {
    rank_kernel<<<dim3(NN / 256, NB), dim3(1024), 0, stream>>>(
        keys, (const float4*)boxes_out, vbyte, order, sbox, vbits, dnm);
    build_kernel<<<dim3(128, 65, NB), dim3(64), 0, stream>>>(sbox, mask, dnm);
    reduce_kernel<<<dim3(NB), dim3(512), 0, stream>>>(mask, vbits, dnm, order,
                                                      keep_out);
  } else {
    rank_kernel<<<dim3(NN / 256, NB), dim3(1024), 0, stream>>>(
        keys, (const float4*)boxes_out, vbyte, order, sbox, vbits, dnm);
    nms_fallback<<<dim3(NB), dim3(1024), 0, stream>>>(sbox, vbits, order,
                                                      keep_out);
  }
}